// Round 9
// baseline (631.776 us; speedup 1.0000x reference)
//
#include <hip/hip_runtime.h>
#include <hip/hip_bf16.h>
#include <math.h>

#define N_SEQ  4096
#define DMODEL 320
#define NHEADS 8
#define DHEAD  40
#define CTXN   77
#define CTXD   768
#define FFI    1280

typedef short s8v __attribute__((ext_vector_type(8)));
typedef short s4v __attribute__((ext_vector_type(4)));
typedef float f4v __attribute__((ext_vector_type(4)));
typedef unsigned short u16;

static __device__ __forceinline__ u16 bf16u(float x) {           // RNE
    unsigned u = __float_as_uint(x);
    return (u16)((u + 0x7FFFu + ((u >> 16) & 1u)) >> 16);
}
static __device__ __forceinline__ float b2f(u16 v) { return __uint_as_float((unsigned)v << 16); }
static __device__ __forceinline__ unsigned pack2(float a, float b) {
    return (unsigned)bf16u(a) | ((unsigned)bf16u(b) << 16);
}

// ---------------- weight pre-convert ----------------
struct WC { const float* s; u16* d; int K, O, trans; };
struct WCs { WC a[12]; };
__global__ __launch_bounds__(256) void wcast_k(WCs P) {
    WC w = P.a[blockIdx.y];
    int e = blockIdx.x * 256 + threadIdx.x;
    if (e >= w.K * w.O) return;
    int o = e / w.K, k = e - o * w.K;
    float v = w.trans ? w.s[(size_t)k * w.O + o] : w.s[e];
    w.d[e] = bf16u(v);
}

// ---------------- GroupNorm stats -> per-channel scale/shift ----------------
__global__ __launch_bounds__(256) void gn_stats_k(const float* __restrict__ x,
                                                  const float* __restrict__ gw, const float* __restrict__ gb,
                                                  float* __restrict__ sc, float* __restrict__ sh) {
    __shared__ float red[512];
    __shared__ float ms[2];
    int g = blockIdx.x, t = threadIdx.x;
    const float* xp = x + (size_t)g * 40960;
    float s = 0.f, ss = 0.f;
    for (int i = t; i < 40960; i += 256) { float v = xp[i]; s += v; ss += v * v; }
    red[t] = s; red[256 + t] = ss;
    __syncthreads();
    for (int st = 128; st > 0; st >>= 1) {
        if (t < st) { red[t] += red[t + st]; red[256 + t] += red[256 + t + st]; }
        __syncthreads();
    }
    if (t == 0) {
        float mean = red[0] / 40960.f;
        float var  = red[256] / 40960.f - mean * mean;
        ms[0] = mean; ms[1] = rsqrtf(var + 1e-6f);
    }
    __syncthreads();
    if (t < 10) {
        int c = g * 10 + t;
        float scv = gw[c] * ms[1];
        sc[c] = scv;
        sh[c] = gb[c] - ms[0] * scv;
    }
}

// ---------------- LayerNorm stats ----------------
__global__ __launch_bounds__(256) void ln_stats_k(const float* __restrict__ in,
                                                  float* __restrict__ mu, float* __restrict__ rs) {
    int row = blockIdx.x * 4 + (threadIdx.x >> 6), l = threadIdx.x & 63;
    const float* p = in + (size_t)row * DMODEL;
    float s = 0.f, ss = 0.f;
#pragma unroll
    for (int j = 0; j < 5; ++j) { float v = p[l + 64 * j]; s += v; ss += v * v; }
    for (int o = 32; o > 0; o >>= 1) { s += __shfl_xor(s, o); ss += __shfl_xor(ss, o); }
    if (l == 0) {
        float mean = s * (1.f / 320.f);
        float var  = ss * (1.f / 320.f) - mean * mean;
        mu[row] = mean;
        rs[row] = rsqrtf(var + 1e-5f);
    }
}

struct GArg { const u16* Wt; const float* bias; float* outf; u16* outb; int ob_mode; };

// ---------------- gemm_v5: 64x64 tile, K-chunk 160, dynamic LDS (2x 64*168 u16) ----------------
// A modes: 0 bf16 row-major | 1 f32 row-major | 2 f32 col-major w/ GN coef | 3 f32 row-major + LN
//          4 attention 4-split combine (Av=Opart bf16, mu=lpart)
// ob_mode: 0 outf f32 row-major | 1 outb bf16 row-major | 2 outb bf16 transposed
//          3 outf f32 transposed + res[o][n] | 4 qkv split
#define GPK 168
__global__ __launch_bounds__(256) void gemm_v5(const void* __restrict__ Av, int a_mode, int lda,
                                               const float* __restrict__ mu, const float* __restrict__ rs,
                                               const float* __restrict__ cw, const float* __restrict__ cb,
                                               GArg g0, GArg g1, GArg g2,
                                               const float* __restrict__ res,
                                               int Mrows, int K, int Oout, int obT_stride) {
    extern __shared__ __align__(16) char smem[];
    u16* As  = (u16*)smem;                       // 64 * GPK
    u16* Wsm = (u16*)(smem + 64 * GPK * 2);      // 64 * GPK
    const int t = threadIdx.x;
    const int w = t >> 6, lane = t & 63, c = lane & 15, quad = lane >> 4;
    const int o0 = blockIdx.x * 64, n0 = blockIdx.y * 64;
    GArg g = (blockIdx.z == 0) ? g0 : ((blockIdx.z == 1) ? g1 : g2);
    const f4v zero = {0.f, 0.f, 0.f, 0.f};
    f4v acc[4] = {zero, zero, zero, zero};
    const s8v z8 = {0, 0, 0, 0, 0, 0, 0, 0};

    for (int k0 = 0; k0 < K; k0 += 160) {
        const int klen = min(160, K - k0);       // always multiple of 32 here
        __syncthreads();
        if (a_mode == 0) {                       // bf16 row-major: 4 thr/row, klen/4 u16 each
            const u16* A = (const u16*)Av;
            int r = t >> 2, qd = t & 3;
            int n = n0 + r;
            const int segs = klen >> 5;          // s8v count
            u16* dst = &As[r * GPK + qd * (klen >> 2)];
            if (n < Mrows) {
                const u16* src = A + (size_t)n * lda + k0 + qd * (klen >> 2);
                for (int i = 0; i < segs; ++i) *(s8v*)(dst + i * 8) = *(const s8v*)(src + i * 8);
            } else {
                for (int i = 0; i < segs; ++i) *(s8v*)(dst + i * 8) = z8;
            }
        } else if (a_mode == 1) {                // f32 row-major
            const float* A = (const float*)Av;
            int r = t >> 2, qd = t & 3;
            int n = n0 + r;
            const int dws = klen >> 3;           // dword pairs
            unsigned* dst = (unsigned*)&As[r * GPK + qd * (klen >> 2)];
            if (n < Mrows) {
                const float* src = A + (size_t)n * lda + k0 + qd * (klen >> 2);
                for (int i = 0; i < dws; ++i) dst[i] = pack2(src[2 * i], src[2 * i + 1]);
            } else {
                for (int i = 0; i < dws; ++i) dst[i] = 0u;
            }
        } else if (a_mode == 2) {                // f32 col-major + GN coef
            const float* A = (const float*)Av;
            for (int e = t; e < 64 * klen; e += 256) {
                int nn = e & 63, kk = e >> 6;
                int n = n0 + nn, kgl = k0 + kk;
                As[nn * GPK + kk] = (n < Mrows) ? bf16u(A[(size_t)kgl * lda + n] * cw[kgl] + cb[kgl]) : (u16)0;
            }
        } else if (a_mode == 3) {                // f32 row-major + LN
            const float* A = (const float*)Av;
            int r = t >> 2, qd = t & 3;
            int n = n0 + r;
            const int dws = klen >> 3;
            unsigned* dst = (unsigned*)&As[r * GPK + qd * (klen >> 2)];
            if (n < Mrows) {
                const int kb = k0 + qd * (klen >> 2);
                const float* src = A + (size_t)n * lda + kb;
                const float* cwp = cw + kb;
                const float* cbp = cb + kb;
                float m_ = mu[n], rr = rs[n];
                for (int i = 0; i < dws; ++i) {
                    float a0 = (src[2 * i]     - m_) * rr * cwp[2 * i]     + cbp[2 * i];
                    float a1 = (src[2 * i + 1] - m_) * rr * cwp[2 * i + 1] + cbp[2 * i + 1];
                    dst[i] = pack2(a0, a1);
                }
            } else {
                for (int i = 0; i < dws; ++i) dst[i] = 0u;
            }
        } else {                                 // 4: combine 4-split attention partials
            const u16* Op = (const u16*)Av;
            const float* lp = mu;
            int r = t >> 2, qd = t & 3;
            int n = n0 + r;
            int hd = (k0 / 40) + qd;             // k0 in {0,160}: each quarter = one head
            unsigned* dst = (unsigned*)&As[r * GPK + qd * 40];
            float den = 0.f;
#pragma unroll
            for (int s = 0; s < 4; ++s) den += lp[(size_t)(s * 8 + hd) * N_SEQ + n];
            float inv = 1.f / den;
#pragma unroll
            for (int seg = 0; seg < 5; ++seg) {
                float a8[8] = {0.f, 0.f, 0.f, 0.f, 0.f, 0.f, 0.f, 0.f};
#pragma unroll
                for (int s = 0; s < 4; ++s) {
                    s8v v8 = *(const s8v*)(Op + ((size_t)(s * 8 + hd) * N_SEQ + n) * DHEAD + seg * 8);
#pragma unroll
                    for (int j = 0; j < 8; ++j) a8[j] += b2f((u16)v8[j]);
                }
#pragma unroll
                for (int i = 0; i < 4; ++i)
                    dst[seg * 4 + i] = pack2(a8[2 * i] * inv, a8[2 * i + 1] * inv);
            }
        }
        // W staging: 64 outs x klen, s8v units
        {
            const int wpr = klen >> 3;
            for (int i = t; i < 64 * wpr; i += 256) {
                int oo = i / wpr, sg = i - oo * wpr;
                *(s8v*)&Wsm[oo * GPK + sg * 8] = *(const s8v*)(g.Wt + (size_t)(o0 + oo) * K + k0 + sg * 8);
            }
        }
        __syncthreads();
        for (int kb = 0; kb < klen; kb += 32) {
            s8v a = *(const s8v*)&As[(w * 16 + c) * GPK + kb + quad * 8];
#pragma unroll
            for (int nt = 0; nt < 4; ++nt) {
                s8v b = *(const s8v*)&Wsm[(nt * 16 + c) * GPK + kb + quad * 8];
                acc[nt] = __builtin_amdgcn_mfma_f32_16x16x32_bf16(a, b, acc[nt], 0, 0, 0);
            }
        }
    }
    // ---------- epilogue ----------
#pragma unroll
    for (int nt = 0; nt < 4; ++nt) {
        int o = o0 + nt * 16 + c;
        float vv[4];
#pragma unroll
        for (int r = 0; r < 4; ++r) vv[r] = acc[nt][r] + (g.bias ? g.bias[o] : 0.f);
        if (g.ob_mode == 3) {
            int nb = n0 + w * 16 + quad * 4;
            const float4 x4 = *(const float4*)(res + (size_t)o * obT_stride + nb);
            float4 o4 = make_float4(vv[0] + x4.x, vv[1] + x4.y, vv[2] + x4.z, vv[3] + x4.w);
            *(float4*)(g.outf + (size_t)o * obT_stride + nb) = o4;
        } else if (g.ob_mode == 4) {
#pragma unroll
            for (int r = 0; r < 4; ++r) {
                int n = n0 + w * 16 + quad * 4 + r;
                u16 bv = bf16u(vv[r]);
                if (o < 320)      g0.outb[(size_t)n * 320 + o] = bv;
                else if (o < 640) g1.outb[(size_t)n * 320 + (o - 320)] = bv;
                else              g2.outb[(size_t)(o - 640) * obT_stride + n] = bv;
            }
        } else {
#pragma unroll
            for (int r = 0; r < 4; ++r) {
                int n = n0 + w * 16 + quad * 4 + r;
                if (n >= Mrows) continue;
                float v = vv[r];
                if (res) v += res[(size_t)n * Oout + o];
                if (g.outf) g.outf[(size_t)n * Oout + o] = v;
                if (g.ob_mode == 1) g.outb[(size_t)n * Oout + o] = bf16u(v);
                else if (g.ob_mode == 2) g.outb[(size_t)o * obT_stride + n] = bf16u(v);
            }
        }
    }
}

// ---------------- gemm_v3 (geglu / ff1 only): 64x64, K-chunk 64 — proven R8 path ----------------
#define GP 72
__global__ __launch_bounds__(256) void gemm_v3(const void* __restrict__ Av, int lda,
                                               const float* __restrict__ mu, const float* __restrict__ rs,
                                               const float* __restrict__ cw, const float* __restrict__ cb,
                                               GArg g0, int Mrows, int K, int Oout, int geglu_off) {
    __shared__ __align__(16) u16 As[64 * GP];
    __shared__ __align__(16) u16 Wsm[64 * GP];
    __shared__ __align__(16) u16 Wgm[64 * GP];
    const int t = threadIdx.x;
    const int w = t >> 6, lane = t & 63, c = lane & 15, quad = lane >> 4;
    const int o0 = blockIdx.x * 64, n0 = blockIdx.y * 64;
    GArg g = g0;
    const f4v zero = {0.f, 0.f, 0.f, 0.f};
    f4v acc[4]  = {zero, zero, zero, zero};
    f4v accg[4] = {zero, zero, zero, zero};

    for (int k0 = 0; k0 < K; k0 += 64) {
        __syncthreads();
        {   // a_mode 3 (LN-fused f32 row-major) — the only mode ff1 needs
            const float* A = (const float*)Av;
            int r = t >> 2, s16 = (t & 3) * 16;
            int n = n0 + r;
            unsigned* dst = (unsigned*)&As[r * GP + s16];
            const float* src = A + (size_t)n * lda + k0 + s16;
            const float* cwp = cw + k0 + s16;
            const float* cbp = cb + k0 + s16;
            float m_ = mu[n], rr = rs[n];
#pragma unroll
            for (int i = 0; i < 8; ++i) {
                float a0 = (src[2 * i]     - m_) * rr * cwp[2 * i]     + cbp[2 * i];
                float a1 = (src[2 * i + 1] - m_) * rr * cwp[2 * i + 1] + cbp[2 * i + 1];
                dst[i] = pack2(a0, a1);
            }
        }
#pragma unroll
        for (int i = t; i < 512; i += 256) {
            int oo = i >> 3, sg = i & 7;
            *(s8v*)&Wsm[oo * GP + sg * 8] = *(const s8v*)(g.Wt + (size_t)(o0 + oo) * K + k0 + sg * 8);
        }
#pragma unroll
        for (int i = t; i < 512; i += 256) {
            int oo = i >> 3, sg = i & 7;
            *(s8v*)&Wgm[oo * GP + sg * 8] = *(const s8v*)(g.Wt + (size_t)(o0 + oo + geglu_off) * K + k0 + sg * 8);
        }
        __syncthreads();
        s8v a0 = *(const s8v*)&As[(w * 16 + c) * GP + quad * 8];
        s8v a1 = *(const s8v*)&As[(w * 16 + c) * GP + 32 + quad * 8];
#pragma unroll
        for (int nt = 0; nt < 4; ++nt) {
            s8v b0 = *(const s8v*)&Wsm[(nt * 16 + c) * GP + quad * 8];
            s8v b1 = *(const s8v*)&Wsm[(nt * 16 + c) * GP + 32 + quad * 8];
            acc[nt] = __builtin_amdgcn_mfma_f32_16x16x32_bf16(a0, b0, acc[nt], 0, 0, 0);
            acc[nt] = __builtin_amdgcn_mfma_f32_16x16x32_bf16(a1, b1, acc[nt], 0, 0, 0);
            s8v q0 = *(const s8v*)&Wgm[(nt * 16 + c) * GP + quad * 8];
            s8v q1 = *(const s8v*)&Wgm[(nt * 16 + c) * GP + 32 + quad * 8];
            accg[nt] = __builtin_amdgcn_mfma_f32_16x16x32_bf16(a0, q0, accg[nt], 0, 0, 0);
            accg[nt] = __builtin_amdgcn_mfma_f32_16x16x32_bf16(a1, q1, accg[nt], 0, 0, 0);
        }
    }
#pragma unroll
    for (int nt = 0; nt < 4; ++nt) {
        int o = o0 + nt * 16 + c;
#pragma unroll
        for (int r = 0; r < 4; ++r) {
            int n = n0 + w * 16 + quad * 4 + r;
            float v = acc[nt][r] + g.bias[o];
            float gg = accg[nt][r] + g.bias[o + geglu_off];
            v = v * 0.5f * gg * (1.f + erff(gg * 0.70710678118654752f));
            g.outb[(size_t)n * Oout + o] = bf16u(v);
        }
    }
}

// ---------------- Self-attention v6: 4-way K-split, truncation P-store ----------------
#define KSP 40
#define PSP 140
#define VP  136
__global__ __launch_bounds__(256) void attn_self6_k(const u16* __restrict__ qb, const u16* __restrict__ kb,
                                                    const u16* __restrict__ vt,
                                                    u16* __restrict__ Opart, float* __restrict__ lpart) {
    __shared__ __align__(16) u16 KsPs[64 * PSP];
    __shared__ __align__(16) u16 Vs[48 * VP];
    const int t = threadIdx.x;
    const int w = t >> 6, lane = t & 63, c = lane & 15, quad = lane >> 4;
    const int hd = blockIdx.y, ks = blockIdx.z;
    const int q0 = blockIdx.x * 64;
    const float SC2 = 0.15811388300841897f * 1.4426950408889634f;
    const f4v zero = {0.f, 0.f, 0.f, 0.f};
    const s8v z8 = {0, 0, 0, 0, 0, 0, 0, 0};

    for (int i = t; i < 8 * VP / 2; i += 256) ((unsigned*)&Vs[40 * VP])[i] = 0u;

    const u16* qrow = qb + (size_t)(q0 + w * 16 + c) * DMODEL + hd * DHEAD;
    s8v qa0 = *(const s8v*)(qrow + quad * 8);
    s8v qa1 = z8;
    if (quad == 0) qa1 = *(const s8v*)(qrow + 32);

    float lacc[4] = {0.f, 0.f, 0.f, 0.f};
    f4v o0 = zero, o1 = zero, o2 = zero;

    for (int kt = 0; kt < 8; ++kt) {
        const int k0 = ks * 1024 + kt * 128;
        __syncthreads();
        for (int i = t; i < 640; i += 256) {
            int r = i / 5, sg = i - r * 5;
            *(s8v*)&KsPs[r * KSP + sg * 8] = *(const s8v*)(kb + (size_t)(k0 + r) * DMODEL + hd * DHEAD + sg * 8);
        }
        for (int i = t; i < 640; i += 256) {
            int d = i >> 4, sg = i & 15;
            *(s8v*)&Vs[d * VP + sg * 8] = *(const s8v*)(vt + (size_t)(hd * DHEAD + d) * N_SEQ + k0 + sg * 8);
        }
        __syncthreads();

        f4v sarr[8];
#pragma unroll
        for (int nt = 0; nt < 8; ++nt) {
            const int kr = nt * 16 + c;
            s8v b0 = *(const s8v*)&KsPs[kr * KSP + quad * 8];
            s8v b1 = z8;
            if (quad == 0) b1 = *(const s8v*)&KsPs[kr * KSP + 32];
            f4v s = __builtin_amdgcn_mfma_f32_16x16x32_bf16(qa0, b0, zero, 0, 0, 0);
            s = __builtin_amdgcn_mfma_f32_16x16x32_bf16(qa1, b1, s, 0, 0, 0);
            sarr[nt] = s;
        }
        __syncthreads();

        u16* psw = &KsPs[(size_t)(w * 16 + quad * 4) * PSP + c];
#pragma unroll
        for (int reg = 0; reg < 8; ++reg) {
            const int colb = (reg >> 2) * 64 + (reg & 3) * 16;
#pragma unroll
            for (int r = 0; r < 4; ++r) {
                float pv = exp2f(sarr[reg][r] * SC2);
                lacc[r] += pv;
                psw[r * PSP + colb] = (u16)(__float_as_uint(pv) >> 16);   // truncate
            }
        }

        const u16* prow = &KsPs[(size_t)(w * 16 + c) * PSP];
#pragma unroll
        for (int h2 = 0; h2 < 2; ++h2) {
            s8v pa0, pa1;
            {
                s4v lo = *(const s4v*)(prow + h2 * 64 + quad * 8);
                s4v hi = *(const s4v*)(prow + h2 * 64 + quad * 8 + 4);
                pa0 = (s8v){lo[0], lo[1], lo[2], lo[3], hi[0], hi[1], hi[2], hi[3]};
                s4v lo2 = *(const s4v*)(prow + h2 * 64 + 32 + quad * 8);
                s4v hi2 = *(const s4v*)(prow + h2 * 64 + 32 + quad * 8 + 4);
                pa1 = (s8v){lo2[0], lo2[1], lo2[2], lo2[3], hi2[0], hi2[1], hi2[2], hi2[3]};
            }
            {
                s8v v0 = *(const s8v*)&Vs[(0 * 16 + c) * VP + h2 * 64 + quad * 8];
                s8v v1 = *(const s8v*)&Vs[(0 * 16 + c) * VP + h2 * 64 + 32 + quad * 8];
                o0 = __builtin_amdgcn_mfma_f32_16x16x32_bf16(pa0, v0, o0, 0, 0, 0);
                o0 = __builtin_amdgcn_mfma_f32_16x16x32_bf16(pa1, v1, o0, 0, 0, 0);
            }
            {
                s8v v0 = *(const s8v*)&Vs[(1 * 16 + c) * VP + h2 * 64 + quad * 8];
                s8v v1 = *(const s8v*)&Vs[(1 * 16 + c) * VP + h2 * 64 + 32 + quad * 8];
                o1 = __builtin_amdgcn_mfma_f32_16x16x32_bf16(pa0, v0, o1, 0, 0, 0);
                o1 = __builtin_amdgcn_mfma_f32_16x16x32_bf16(pa1, v1, o1, 0, 0, 0);
            }
            {
                s8v v0 = *(const s8v*)&Vs[(2 * 16 + c) * VP + h2 * 64 + quad * 8];
                s8v v1 = *(const s8v*)&Vs[(2 * 16 + c) * VP + h2 * 64 + 32 + quad * 8];
                o2 = __builtin_amdgcn_mfma_f32_16x16x32_bf16(pa0, v0, o2, 0, 0, 0);
                o2 = __builtin_amdgcn_mfma_f32_16x16x32_bf16(pa1, v1, o2, 0, 0, 0);
            }
        }
    }

    const size_t pb = (size_t)(ks * 8 + hd) * N_SEQ;
#pragma unroll
    for (int r = 0; r < 4; ++r) {
        float l = lacc[r];
        l += __shfl_xor(l, 1); l += __shfl_xor(l, 2); l += __shfl_xor(l, 4); l += __shfl_xor(l, 8);
        int q = q0 + w * 16 + quad * 4 + r;
        u16* op = Opart + (pb + q) * DHEAD;
        op[c]      = bf16u(o0[r]);
        op[16 + c] = bf16u(o1[r]);
        if (c < 8) op[32 + c] = bf16u(o2[r]);
        if (c == 0) lpart[pb + q] = l;
    }
}

// ---------------- Cross-attention (M=77) ----------------
__global__ __launch_bounds__(256) void attn_cross2_k(const u16* __restrict__ q, const float* __restrict__ kc,
                                                     const float* __restrict__ vc, u16* __restrict__ out) {
    __shared__ float Pl[4][128];
    const int t = threadIdx.x, w = t >> 6, l = t & 63;
    const int gw = blockIdx.x * 4 + w;
    const int row = gw >> 3, hd = gw & 7;
    const float scale = 0.15811388300841897f;
    float qv[40];
    {
        const u16* qp = q + (size_t)row * DMODEL + hd * DHEAD;
#pragma unroll
        for (int i = 0; i < 5; ++i) {
            s8v v8 = *(const s8v*)(qp + i * 8);
#pragma unroll
            for (int j = 0; j < 8; ++j) qv[i * 8 + j] = b2f((u16)v8[j]) * scale;
        }
    }
    float s1 = -1e30f, s2 = -1e30f;
    if (l < CTXN) {
        const float* kp = kc + (size_t)l * DMODEL + hd * DHEAD;
        float s = 0.f;
#pragma unroll
        for (int i = 0; i < 40; ++i) s += qv[i] * kp[i];
        s1 = s;
    }
    if (l + 64 < CTXN) {
        const float* kp = kc + (size_t)(l + 64) * DMODEL + hd * DHEAD;
        float s = 0.f;
#pragma unroll
        for (int i = 0; i < 40; ++i) s += qv[i] * kp[i];
        s2 = s;
    }
    float mx = fmaxf(s1, s2);
    for (int o = 32; o > 0; o >>= 1) mx = fmaxf(mx, __shfl_xor(mx, o));
    float p1 = (l < CTXN) ? __expf(s1 - mx) : 0.f;
    float p2 = (l + 64 < CTXN) ? __expf(s2 - mx) : 0.f;
    float ps = p1 + p2;
    for (int o = 32; o > 0; o >>= 1) ps += __shfl_xor(ps, o);
    Pl[w][l] = p1;
    Pl[w][l + 64] = p2;
    if (l < DHEAD) {
        float acc = 0.f;
        for (int j = 0; j < CTXN; ++j) acc += Pl[w][j] * vc[(size_t)j * DMODEL + hd * DHEAD + l];
        out[(size_t)row * DMODEL + hd * DHEAD + l] = bf16u(acc / ps);
    }
}

extern "C" void kernel_launch(void* const* d_in, const int* in_sizes, int n_in,
                              void* d_out, int out_size, void* d_ws, size_t ws_size,
                              hipStream_t stream) {
    const float* x      = (const float*)d_in[0];
    const float* ctx    = (const float*)d_in[1];
    const float* gn_w   = (const float*)d_in[2];
    const float* gn_b   = (const float*)d_in[3];
    const float* pin_w  = (const float*)d_in[4];
    const float* pin_b  = (const float*)d_in[5];
    const float* ln1_w  = (const float*)d_in[6];
    const float* ln1_b  = (const float*)d_in[7];
    const float* q1     = (const float*)d_in[8];
    const float* k1     = (const float*)d_in[9];
    const float* v1     = (const float*)d_in[10];
    const float* o1_w   = (const float*)d_in[11];
    const float* o1_b   = (const float*)d_in[12];
    const float* ln2_w  = (const float*)d_in[13];
    const float* ln2_b  = (const float*)d_in[14];
    const float* q2     = (const float*)d_in[15];
    const float* k2     = (const float*)d_in[16];
    const float* v2     = (const float*)d_in[17];
    const float* o2_w   = (const float*)d_in[18];
    const float* o2_b   = (const float*)d_in[19];
    const float* ln3_w  = (const float*)d_in[20];
    const float* ln3_b  = (const float*)d_in[21];
    const float* ff1_w  = (const float*)d_in[22];
    const float* ff1_b  = (const float*)d_in[23];
    const float* ff2_w  = (const float*)d_in[24];
    const float* ff2_b  = (const float*)d_in[25];
    const float* pout_w = (const float*)d_in[26];
    const float* pout_b = (const float*)d_in[27];
    float* out = (float*)d_out;

    char* base = (char*)d_ws;
    float* h     = (float*)(base);                        //  0 .. 5.24 MB
    u16*   qb16  = (u16*)(base + 5242880);
    u16*   kb16  = (u16*)(base + 7864320);
    u16*   vt16  = (u16*)(base + 10485760);               // [320][4096]
    u16*   ao16  = (u16*)(base + 13107200);
    u16*   ffg16 = (u16*)(base + 5242880);                // FF alias
    u16*   wbase = (u16*)(base + 15728640);
    u16* pinT  = wbase;
    u16* q1T   = pinT  + 102400;
    u16* k1T   = q1T   + 102400;
    u16* v1T   = k1T   + 102400;
    u16* o1T   = v1T   + 102400;
    u16* q2T   = o1T   + 102400;
    u16* o2T   = q2T   + 102400;
    u16* k2T   = o2T   + 102400;
    u16* v2T   = k2T   + 245760;
    u16* ff1T  = v2T   + 245760;
    u16* ff2T  = ff1T  + 819200;
    u16* poutT = ff2T  + 409600;                          // ends 20,807,680
    float* lnmu = (float*)(base + 20807680);              // 4096
    float* lnrs = lnmu + 4096;
    float* k2f  = lnrs + 4096;                            // 77*320 pad 25600
    float* v2f  = k2f + 25600;
    u16*   Opart = (u16*)(v2f + 25600);                   // 4*8*4096*40 bf16 = 10.49 MB
    float* lpart = (float*)(Opart + (size_t)4 * 8 * 4096 * 40);   // 4*8*4096 f32
    float* gnsc  = lpart + 4 * 8 * 4096;                  // 320
    float* gnsh  = gnsc + 320;                            // total ~32.06 MB

    // 0. weights -> bf16 [O][K]
    WCs wd;
    wd.a[0]  = {pin_w,  pinT,  320,  320,  0};
    wd.a[1]  = {q1,     q1T,   320,  320,  1};
    wd.a[2]  = {k1,     k1T,   320,  320,  1};
    wd.a[3]  = {v1,     v1T,   320,  320,  1};
    wd.a[4]  = {o1_w,   o1T,   320,  320,  1};
    wd.a[5]  = {q2,     q2T,   320,  320,  1};
    wd.a[6]  = {o2_w,   o2T,   320,  320,  1};
    wd.a[7]  = {k2,     k2T,   768,  320,  1};
    wd.a[8]  = {v2,     v2T,   768,  320,  1};
    wd.a[9]  = {ff1_w,  ff1T,  320,  2560, 1};
    wd.a[10] = {ff2_w,  ff2T,  1280, 320,  1};
    wd.a[11] = {pout_w, poutT, 320,  320,  0};
    wcast_k<<<dim3(3200, 12), 256, 0, stream>>>(wd);

    GArg gz = {nullptr, nullptr, nullptr, nullptr, 0};
    const size_t GSM = (size_t)2 * 64 * GPK * 2;          // 43008 B dynamic LDS

    // 1. GN stats; proj_in (GN fused in staging)
    gn_stats_k<<<32, 256, 0, stream>>>(x, gn_w, gn_b, gnsc, gnsh);
    {
        GArg g0 = {pinT, pin_b, h, nullptr, 0};
        gemm_v5<<<dim3(5, 64, 1), 256, GSM, stream>>>(x, 2, 4096, nullptr, nullptr, gnsc, gnsh,
                                                      g0, gz, gz, nullptr, 4096, 320, 320, 0);
    }
    // 2. qkv fused (LN1 in staging)
    ln_stats_k<<<1024, 256, 0, stream>>>(h, lnmu, lnrs);
    {
        GArg g0 = {q1T, nullptr, nullptr, qb16, 4};
        GArg g1 = {nullptr, nullptr, nullptr, kb16, 0};
        GArg g2 = {nullptr, nullptr, nullptr, vt16, 0};
        gemm_v5<<<dim3(15, 64, 1), 256, GSM, stream>>>(h, 3, 320, lnmu, lnrs, ln1_w, ln1_b,
                                                       g0, g1, g2, nullptr, 4096, 320, 960, 4096);
    }
    attn_self6_k<<<dim3(64, 8, 4), 256, 0, stream>>>(qb16, kb16, vt16, Opart, lpart);
    // 3. o1 proj: A = combined 4-split partials, residual h
    {
        GArg g0 = {o1T, o1_b, h, nullptr, 0};
        gemm_v5<<<dim3(5, 64, 1), 256, GSM, stream>>>(Opart, 4, 0, lpart, nullptr, nullptr, nullptr,
                                                      g0, gz, gz, h, 4096, 320, 320, 0);
    }
    // 4. cross-attention block (LN2 in q2 staging)
    ln_stats_k<<<1024, 256, 0, stream>>>(h, lnmu, lnrs);
    {
        GArg g0 = {q2T, nullptr, nullptr, qb16, 1};
        gemm_v5<<<dim3(5, 64, 1), 256, GSM, stream>>>(h, 3, 320, lnmu, lnrs, ln2_w, ln2_b,
                                                      g0, gz, gz, nullptr, 4096, 320, 320, 0);
    }
    {
        GArg g0 = {k2T, nullptr, k2f, nullptr, 0};
        GArg g1 = {v2T, nullptr, v2f, nullptr, 0};
        gemm_v5<<<dim3(5, 2, 2), 256, GSM, stream>>>(ctx, 1, 768, nullptr, nullptr, nullptr, nullptr,
                                                     g0, g1, gz, nullptr, 77, 768, 320, 0);
    }
    attn_cross2_k<<<8192, 256, 0, stream>>>(qb16, k2f, v2f, ao16);
    {
        GArg g0 = {o2T, o2_b, h, nullptr, 0};
        gemm_v5<<<dim3(5, 64, 1), 256, GSM, stream>>>(ao16, 0, 320, nullptr, nullptr, nullptr, nullptr,
                                                      g0, gz, gz, h, 4096, 320, 320, 0);
    }
    // 5. GEGLU FF (LN3 in ff1 staging; ff1 via geglu kernel)
    ln_stats_k<<<1024, 256, 0, stream>>>(h, lnmu, lnrs);
    {
        GArg g0 = {ff1T, ff1_b, nullptr, ffg16, 1};
        gemm_v3<<<dim3(20, 64, 1), 256, 0, stream>>>(h, 320, lnmu, lnrs, ln3_w, ln3_b,
                                                     g0, 4096, 320, 1280, 1280);
    }
    {
        GArg g0 = {ff2T, ff2_b, h, nullptr, 0};
        gemm_v5<<<dim3(5, 64, 1), 256, GSM, stream>>>(ffg16, 0, 1280, nullptr, nullptr, nullptr, nullptr,
                                                      g0, gz, gz, h, 4096, 1280, 320, 0);
    }
    // 6. proj_out + input residual
    {
        GArg g0 = {poutT, pout_b, out, nullptr, 3};
        gemm_v5<<<dim3(5, 64, 1), 256, GSM, stream>>>(h, 1, 320, nullptr, nullptr, nullptr, nullptr,
                                                      g0, gz, gz, x, 4096, 320, 320, 4096);
    }
}

// Round 10
// 556.105 us; speedup vs baseline: 1.1361x; 1.1361x over previous
//
#include <hip/hip_runtime.h>
#include <hip/hip_bf16.h>
#include <math.h>

#define N_SEQ  4096
#define DMODEL 320
#define NHEADS 8
#define DHEAD  40
#define CTXN   77
#define CTXD   768
#define FFI    1280

typedef short s8v __attribute__((ext_vector_type(8)));
typedef short s4v __attribute__((ext_vector_type(4)));
typedef float f4v __attribute__((ext_vector_type(4)));
typedef unsigned short u16;

static __device__ __forceinline__ u16 bf16u(float x) {           // RNE
    unsigned u = __float_as_uint(x);
    return (u16)((u + 0x7FFFu + ((u >> 16) & 1u)) >> 16);
}
static __device__ __forceinline__ float b2f(u16 v) { return __uint_as_float((unsigned)v << 16); }
static __device__ __forceinline__ unsigned pack2(float a, float b) {
    return (unsigned)bf16u(a) | ((unsigned)bf16u(b) << 16);
}

// ---------------- weight pre-convert v2: coalesced tiled transpose ----------------
struct WC { const float* s; u16* d; int K, O, trans; };
struct WCs { WC a[12]; };
__global__ __launch_bounds__(256) void wcast2_k(WCs P) {
    __shared__ float tile[32][33];
    WC w = P.a[blockIdx.y];
    if (w.trans) {            // src [K][O] -> dst [O][K], 32x32 tiles (K,O multiples of 32)
        int ntk = w.K >> 5, nto = w.O >> 5;
        int tid = blockIdx.x;
        if (tid >= ntk * nto) return;
        int tk = tid % ntk, to = tid / ntk;
        int lr = threadIdx.x >> 5, lc = threadIdx.x & 31;
#pragma unroll
        for (int p = 0; p < 4; ++p) {
            int k = tk * 32 + p * 8 + lr;
            tile[p * 8 + lr][lc] = w.s[(size_t)k * w.O + to * 32 + lc];
        }
        __syncthreads();
#pragma unroll
        for (int p = 0; p < 4; ++p) {
            int o = to * 32 + p * 8 + lr;
            w.d[(size_t)o * w.K + tk * 32 + lc] = bf16u(tile[lc][p * 8 + lr]);
        }
    } else {                  // already [O][K]: straight convert
        int nel = w.K * w.O;
        for (int e = blockIdx.x * 256 + threadIdx.x; e < nel; e += gridDim.x * 256)
            w.d[e] = bf16u(w.s[e]);
    }
}

// ---------------- GroupNorm stats -> per-channel scale/shift ----------------
__global__ __launch_bounds__(256) void gn_stats_k(const float* __restrict__ x,
                                                  const float* __restrict__ gw, const float* __restrict__ gb,
                                                  float* __restrict__ sc, float* __restrict__ sh) {
    __shared__ float red[512];
    __shared__ float ms[2];
    int g = blockIdx.x, t = threadIdx.x;
    const float* xp = x + (size_t)g * 40960;
    float s = 0.f, ss = 0.f;
    for (int i = t; i < 40960; i += 256) { float v = xp[i]; s += v; ss += v * v; }
    red[t] = s; red[256 + t] = ss;
    __syncthreads();
    for (int st = 128; st > 0; st >>= 1) {
        if (t < st) { red[t] += red[t + st]; red[256 + t] += red[256 + t + st]; }
        __syncthreads();
    }
    if (t == 0) {
        float mean = red[0] / 40960.f;
        float var  = red[256] / 40960.f - mean * mean;
        ms[0] = mean; ms[1] = rsqrtf(var + 1e-6f);
    }
    __syncthreads();
    if (t < 10) {
        int c = g * 10 + t;
        float scv = gw[c] * ms[1];
        sc[c] = scv;
        sh[c] = gb[c] - ms[0] * scv;
    }
}

// ---------------- LayerNorm stats ----------------
__global__ __launch_bounds__(256) void ln_stats_k(const float* __restrict__ in,
                                                  float* __restrict__ mu, float* __restrict__ rs) {
    int row = blockIdx.x * 4 + (threadIdx.x >> 6), l = threadIdx.x & 63;
    const float* p = in + (size_t)row * DMODEL;
    float s = 0.f, ss = 0.f;
#pragma unroll
    for (int j = 0; j < 5; ++j) { float v = p[l + 64 * j]; s += v; ss += v * v; }
    for (int o = 32; o > 0; o >>= 1) { s += __shfl_xor(s, o); ss += __shfl_xor(ss, o); }
    if (l == 0) {
        float mean = s * (1.f / 320.f);
        float var  = ss * (1.f / 320.f) - mean * mean;
        mu[row] = mean;
        rs[row] = rsqrtf(var + 1e-5f);
    }
}

struct GArg { const u16* Wt; const float* bias; float* outf; u16* outb; int ob_mode; };
#define GP 72

// ---------------- gemm_t<SITE>: 64x64 tile, K-chunk 64 (proven R8 config), per-site names ----------------
// A modes: 0 bf16 row-major | 1 f32 row-major | 2 f32 col-major + GN coef | 3 f32 row-major + LN
//          4 attention 2-split combine (Av=Opart bf16, mu=lpart)
// ob_mode: 0 outf f32 row-major | 1 outb bf16 row-major | 2 outb bf16 transposed
//          3 outf f32 transposed + res[o][n] | 4 qkv split
template<int SITE>
__global__ __launch_bounds__(256) void gemm_t(const void* __restrict__ Av, int a_mode, int lda,
                                              const float* __restrict__ mu, const float* __restrict__ rs,
                                              const float* __restrict__ cw, const float* __restrict__ cb,
                                              GArg g0, GArg g1, GArg g2,
                                              const float* __restrict__ res,
                                              int Mrows, int K, int Oout, int obT_stride) {
    __shared__ __align__(16) u16 As[64 * GP];
    __shared__ __align__(16) u16 Wsm[64 * GP];
    const int t = threadIdx.x;
    const int w = t >> 6, lane = t & 63, c = lane & 15, quad = lane >> 4;
    const int o0 = blockIdx.x * 64, n0 = blockIdx.y * 64;
    GArg g = (blockIdx.z == 0) ? g0 : ((blockIdx.z == 1) ? g1 : g2);
    const f4v zero = {0.f, 0.f, 0.f, 0.f};
    f4v acc[4] = {zero, zero, zero, zero};
    const s8v z8 = {0, 0, 0, 0, 0, 0, 0, 0};

    for (int k0 = 0; k0 < K; k0 += 64) {
        __syncthreads();
        if (a_mode == 0) {
            const u16* A = (const u16*)Av;
#pragma unroll
            for (int i = t; i < 512; i += 256) {
                int r = i >> 3, sg = i & 7;
                int n = n0 + r;
                *(s8v*)&As[r * GP + sg * 8] =
                    (n < Mrows) ? *(const s8v*)(A + (size_t)n * lda + k0 + sg * 8) : z8;
            }
        } else if (a_mode == 1) {
            const float* A = (const float*)Av;
            int r = t >> 2, s16 = (t & 3) * 16;
            int n = n0 + r;
            unsigned* dst = (unsigned*)&As[r * GP + s16];
            if (n < Mrows) {
                const float* src = A + (size_t)n * lda + k0 + s16;
#pragma unroll
                for (int i = 0; i < 8; ++i) dst[i] = pack2(src[2 * i], src[2 * i + 1]);
            } else {
#pragma unroll
                for (int i = 0; i < 8; ++i) dst[i] = 0u;
            }
        } else if (a_mode == 2) {
            const float* A = (const float*)Av;
#pragma unroll
            for (int j = 0; j < 16; ++j) {
                int e = t + 256 * j; int nn = e & 63, kk = e >> 6;
                int n = n0 + nn, kgl = k0 + kk;
                As[nn * GP + kk] = (n < Mrows) ? bf16u(A[(size_t)kgl * lda + n] * cw[kgl] + cb[kgl]) : (u16)0;
            }
        } else if (a_mode == 3) {
            const float* A = (const float*)Av;
            int r = t >> 2, s16 = (t & 3) * 16;
            int n = n0 + r;
            unsigned* dst = (unsigned*)&As[r * GP + s16];
            if (n < Mrows) {
                const float* src = A + (size_t)n * lda + k0 + s16;
                const float* cwp = cw + k0 + s16;
                const float* cbp = cb + k0 + s16;
                float m_ = mu[n], rr = rs[n];
#pragma unroll
                for (int i = 0; i < 8; ++i) {
                    float a0 = (src[2 * i]     - m_) * rr * cwp[2 * i]     + cbp[2 * i];
                    float a1 = (src[2 * i + 1] - m_) * rr * cwp[2 * i + 1] + cbp[2 * i + 1];
                    dst[i] = pack2(a0, a1);
                }
            } else {
#pragma unroll
                for (int i = 0; i < 8; ++i) dst[i] = 0u;
            }
        } else {   // 4: combine 2-split attention partials during staging
            const u16* Op = (const u16*)Av;
            const float* lp = mu;
            int r = t >> 2, s16 = (t & 3) * 16;
            int n = n0 + r;
            unsigned* dst = (unsigned*)&As[r * GP + s16];
            int ch0 = k0 + s16;
            int hdA = ch0 / 40;
            int hdB = (ch0 + 15) / 40;
            float invA = 1.f / (lp[(size_t)hdA * N_SEQ + n] + lp[(size_t)(8 + hdA) * N_SEQ + n]);
            float invB = (hdB == hdA) ? invA
                       : 1.f / (lp[(size_t)hdB * N_SEQ + n] + lp[(size_t)(8 + hdB) * N_SEQ + n]);
            float vals[16];
#pragma unroll
            for (int i = 0; i < 16; ++i) {
                int ch = ch0 + i;
                int hd = ch / 40;
                int d  = ch - hd * 40;
                float num = b2f(Op[((size_t)hd * N_SEQ + n) * DHEAD + d])
                          + b2f(Op[((size_t)(8 + hd) * N_SEQ + n) * DHEAD + d]);
                vals[i] = num * ((hd == hdA) ? invA : invB);
            }
#pragma unroll
            for (int i = 0; i < 8; ++i) dst[i] = pack2(vals[2 * i], vals[2 * i + 1]);
        }
#pragma unroll
        for (int i = t; i < 512; i += 256) {
            int oo = i >> 3, sg = i & 7;
            *(s8v*)&Wsm[oo * GP + sg * 8] = *(const s8v*)(g.Wt + (size_t)(o0 + oo) * K + k0 + sg * 8);
        }
        __syncthreads();
        s8v a0 = *(const s8v*)&As[(w * 16 + c) * GP + quad * 8];
        s8v a1 = *(const s8v*)&As[(w * 16 + c) * GP + 32 + quad * 8];
#pragma unroll
        for (int nt = 0; nt < 4; ++nt) {
            s8v b0 = *(const s8v*)&Wsm[(nt * 16 + c) * GP + quad * 8];
            s8v b1 = *(const s8v*)&Wsm[(nt * 16 + c) * GP + 32 + quad * 8];
            acc[nt] = __builtin_amdgcn_mfma_f32_16x16x32_bf16(a0, b0, acc[nt], 0, 0, 0);
            acc[nt] = __builtin_amdgcn_mfma_f32_16x16x32_bf16(a1, b1, acc[nt], 0, 0, 0);
        }
    }
#pragma unroll
    for (int nt = 0; nt < 4; ++nt) {
        int o = o0 + nt * 16 + c;
        float vv[4];
#pragma unroll
        for (int r = 0; r < 4; ++r) vv[r] = acc[nt][r] + (g.bias ? g.bias[o] : 0.f);
        if (g.ob_mode == 3) {
            int nb = n0 + w * 16 + quad * 4;
            const float4 x4 = *(const float4*)(res + (size_t)o * obT_stride + nb);
            float4 o4 = make_float4(vv[0] + x4.x, vv[1] + x4.y, vv[2] + x4.z, vv[3] + x4.w);
            *(float4*)(g.outf + (size_t)o * obT_stride + nb) = o4;
        } else if (g.ob_mode == 4) {
#pragma unroll
            for (int r = 0; r < 4; ++r) {
                int n = n0 + w * 16 + quad * 4 + r;
                u16 bv = bf16u(vv[r]);
                if (o < 320)      g0.outb[(size_t)n * 320 + o] = bv;
                else if (o < 640) g1.outb[(size_t)n * 320 + (o - 320)] = bv;
                else              g2.outb[(size_t)(o - 640) * obT_stride + n] = bv;
            }
        } else {
#pragma unroll
            for (int r = 0; r < 4; ++r) {
                int n = n0 + w * 16 + quad * 4 + r;
                if (n >= Mrows) continue;
                float v = vv[r];
                if (res) v += res[(size_t)n * Oout + o];
                if (g.outf) g.outf[(size_t)n * Oout + o] = v;
                if (g.ob_mode == 1) g.outb[(size_t)n * Oout + o] = bf16u(v);
                else if (g.ob_mode == 2) g.outb[(size_t)o * obT_stride + n] = bf16u(v);
            }
        }
    }
}

// ---------------- gemm_gg: ff1 GEGLU (LN staging), K-chunk 64 ----------------
__global__ __launch_bounds__(256) void gemm_gg(const float* __restrict__ A, int lda,
                                               const float* __restrict__ mu, const float* __restrict__ rs,
                                               const float* __restrict__ cw, const float* __restrict__ cb,
                                               const u16* __restrict__ Wt, const float* __restrict__ bias,
                                               u16* __restrict__ outb,
                                               int K, int Oout, int geglu_off) {
    __shared__ __align__(16) u16 As[64 * GP];
    __shared__ __align__(16) u16 Wsm[64 * GP];
    __shared__ __align__(16) u16 Wgm[64 * GP];
    const int t = threadIdx.x;
    const int w = t >> 6, lane = t & 63, c = lane & 15, quad = lane >> 4;
    const int o0 = blockIdx.x * 64, n0 = blockIdx.y * 64;
    const f4v zero = {0.f, 0.f, 0.f, 0.f};
    f4v acc[4]  = {zero, zero, zero, zero};
    f4v accg[4] = {zero, zero, zero, zero};

    for (int k0 = 0; k0 < K; k0 += 64) {
        __syncthreads();
        {
            int r = t >> 2, s16 = (t & 3) * 16;
            int n = n0 + r;
            unsigned* dst = (unsigned*)&As[r * GP + s16];
            const float* src = A + (size_t)n * lda + k0 + s16;
            const float* cwp = cw + k0 + s16;
            const float* cbp = cb + k0 + s16;
            float m_ = mu[n], rr = rs[n];
#pragma unroll
            for (int i = 0; i < 8; ++i) {
                float a0 = (src[2 * i]     - m_) * rr * cwp[2 * i]     + cbp[2 * i];
                float a1 = (src[2 * i + 1] - m_) * rr * cwp[2 * i + 1] + cbp[2 * i + 1];
                dst[i] = pack2(a0, a1);
            }
        }
#pragma unroll
        for (int i = t; i < 512; i += 256) {
            int oo = i >> 3, sg = i & 7;
            *(s8v*)&Wsm[oo * GP + sg * 8] = *(const s8v*)(Wt + (size_t)(o0 + oo) * K + k0 + sg * 8);
        }
#pragma unroll
        for (int i = t; i < 512; i += 256) {
            int oo = i >> 3, sg = i & 7;
            *(s8v*)&Wgm[oo * GP + sg * 8] = *(const s8v*)(Wt + (size_t)(o0 + oo + geglu_off) * K + k0 + sg * 8);
        }
        __syncthreads();
        s8v a0 = *(const s8v*)&As[(w * 16 + c) * GP + quad * 8];
        s8v a1 = *(const s8v*)&As[(w * 16 + c) * GP + 32 + quad * 8];
#pragma unroll
        for (int nt = 0; nt < 4; ++nt) {
            s8v b0 = *(const s8v*)&Wsm[(nt * 16 + c) * GP + quad * 8];
            s8v b1 = *(const s8v*)&Wsm[(nt * 16 + c) * GP + 32 + quad * 8];
            acc[nt] = __builtin_amdgcn_mfma_f32_16x16x32_bf16(a0, b0, acc[nt], 0, 0, 0);
            acc[nt] = __builtin_amdgcn_mfma_f32_16x16x32_bf16(a1, b1, acc[nt], 0, 0, 0);
            s8v q0 = *(const s8v*)&Wgm[(nt * 16 + c) * GP + quad * 8];
            s8v q1 = *(const s8v*)&Wgm[(nt * 16 + c) * GP + 32 + quad * 8];
            accg[nt] = __builtin_amdgcn_mfma_f32_16x16x32_bf16(a0, q0, accg[nt], 0, 0, 0);
            accg[nt] = __builtin_amdgcn_mfma_f32_16x16x32_bf16(a1, q1, accg[nt], 0, 0, 0);
        }
    }
#pragma unroll
    for (int nt = 0; nt < 4; ++nt) {
        int o = o0 + nt * 16 + c;
#pragma unroll
        for (int r = 0; r < 4; ++r) {
            int n = n0 + w * 16 + quad * 4 + r;
            float v = acc[nt][r] + bias[o];
            float gg = accg[nt][r] + bias[o + geglu_off];
            v = v * 0.5f * gg * (1.f + erff(gg * 0.70710678118654752f));
            outb[(size_t)n * Oout + o] = bf16u(v);
        }
    }
}

// ---------------- Self-attention v5 (R8 proven): 2-split, 31KB LDS, RNE P-store ----------------
#define KSP 40
#define PSP 140
#define VP  136
__global__ __launch_bounds__(256) void attn_self5_k(const u16* __restrict__ qb, const u16* __restrict__ kb,
                                                    const u16* __restrict__ vt,
                                                    u16* __restrict__ Opart, float* __restrict__ lpart) {
    __shared__ __align__(16) u16 KsPs[64 * PSP];
    __shared__ __align__(16) u16 Vs[48 * VP];
    const int t = threadIdx.x;
    const int w = t >> 6, lane = t & 63, c = lane & 15, quad = lane >> 4;
    const int hd = blockIdx.y, ks = blockIdx.z;
    const int q0 = blockIdx.x * 64;
    const float SC2 = 0.15811388300841897f * 1.4426950408889634f;
    const f4v zero = {0.f, 0.f, 0.f, 0.f};
    const s8v z8 = {0, 0, 0, 0, 0, 0, 0, 0};

    for (int i = t; i < 8 * VP / 2; i += 256) ((unsigned*)&Vs[40 * VP])[i] = 0u;

    const u16* qrow = qb + (size_t)(q0 + w * 16 + c) * DMODEL + hd * DHEAD;
    s8v qa0 = *(const s8v*)(qrow + quad * 8);
    s8v qa1 = z8;
    if (quad == 0) qa1 = *(const s8v*)(qrow + 32);

    float lacc[4] = {0.f, 0.f, 0.f, 0.f};
    f4v o0 = zero, o1 = zero, o2 = zero;

    for (int kt = 0; kt < 16; ++kt) {
        const int k0 = ks * 2048 + kt * 128;
        __syncthreads();
        for (int i = t; i < 640; i += 256) {
            int r = i / 5, sg = i - r * 5;
            *(s8v*)&KsPs[r * KSP + sg * 8] = *(const s8v*)(kb + (size_t)(k0 + r) * DMODEL + hd * DHEAD + sg * 8);
        }
        for (int i = t; i < 640; i += 256) {
            int d = i >> 4, sg = i & 15;
            *(s8v*)&Vs[d * VP + sg * 8] = *(const s8v*)(vt + (size_t)(hd * DHEAD + d) * N_SEQ + k0 + sg * 8);
        }
        __syncthreads();

        f4v sarr[8];
#pragma unroll
        for (int nt = 0; nt < 8; ++nt) {
            const int kr = nt * 16 + c;
            s8v b0 = *(const s8v*)&KsPs[kr * KSP + quad * 8];
            s8v b1 = z8;
            if (quad == 0) b1 = *(const s8v*)&KsPs[kr * KSP + 32];
            f4v s = __builtin_amdgcn_mfma_f32_16x16x32_bf16(qa0, b0, zero, 0, 0, 0);
            s = __builtin_amdgcn_mfma_f32_16x16x32_bf16(qa1, b1, s, 0, 0, 0);
            sarr[nt] = s;
        }
        __syncthreads();

        u16* psw = &KsPs[(size_t)(w * 16 + quad * 4) * PSP + c];
#pragma unroll
        for (int reg = 0; reg < 8; ++reg) {
            const int colb = (reg >> 2) * 64 + (reg & 3) * 16;
#pragma unroll
            for (int r = 0; r < 4; ++r) {
                float pv = exp2f(sarr[reg][r] * SC2);
                lacc[r] += pv;
                psw[r * PSP + colb] = (u16)((__float_as_uint(pv) + 0x8000u) >> 16);
            }
        }

        const u16* prow = &KsPs[(size_t)(w * 16 + c) * PSP];
#pragma unroll
        for (int h2 = 0; h2 < 2; ++h2) {
            s8v pa0, pa1;
            {
                s4v lo = *(const s4v*)(prow + h2 * 64 + quad * 8);
                s4v hi = *(const s4v*)(prow + h2 * 64 + quad * 8 + 4);
                pa0 = (s8v){lo[0], lo[1], lo[2], lo[3], hi[0], hi[1], hi[2], hi[3]};
                s4v lo2 = *(const s4v*)(prow + h2 * 64 + 32 + quad * 8);
                s4v hi2 = *(const s4v*)(prow + h2 * 64 + 32 + quad * 8 + 4);
                pa1 = (s8v){lo2[0], lo2[1], lo2[2], lo2[3], hi2[0], hi2[1], hi2[2], hi2[3]};
            }
            {
                s8v v0 = *(const s8v*)&Vs[(0 * 16 + c) * VP + h2 * 64 + quad * 8];
                s8v v1 = *(const s8v*)&Vs[(0 * 16 + c) * VP + h2 * 64 + 32 + quad * 8];
                o0 = __builtin_amdgcn_mfma_f32_16x16x32_bf16(pa0, v0, o0, 0, 0, 0);
                o0 = __builtin_amdgcn_mfma_f32_16x16x32_bf16(pa1, v1, o0, 0, 0, 0);
            }
            {
                s8v v0 = *(const s8v*)&Vs[(1 * 16 + c) * VP + h2 * 64 + quad * 8];
                s8v v1 = *(const s8v*)&Vs[(1 * 16 + c) * VP + h2 * 64 + 32 + quad * 8];
                o1 = __builtin_amdgcn_mfma_f32_16x16x32_bf16(pa0, v0, o1, 0, 0, 0);
                o1 = __builtin_amdgcn_mfma_f32_16x16x32_bf16(pa1, v1, o1, 0, 0, 0);
            }
            {
                s8v v0 = *(const s8v*)&Vs[(2 * 16 + c) * VP + h2 * 64 + quad * 8];
                s8v v1 = *(const s8v*)&Vs[(2 * 16 + c) * VP + h2 * 64 + 32 + quad * 8];
                o2 = __builtin_amdgcn_mfma_f32_16x16x32_bf16(pa0, v0, o2, 0, 0, 0);
                o2 = __builtin_amdgcn_mfma_f32_16x16x32_bf16(pa1, v1, o2, 0, 0, 0);
            }
        }
    }

    const size_t pb = (size_t)(ks * 8 + hd) * N_SEQ;
#pragma unroll
    for (int r = 0; r < 4; ++r) {
        float l = lacc[r];
        l += __shfl_xor(l, 1); l += __shfl_xor(l, 2); l += __shfl_xor(l, 4); l += __shfl_xor(l, 8);
        int q = q0 + w * 16 + quad * 4 + r;
        u16* op = Opart + (pb + q) * DHEAD;
        op[c]      = bf16u(o0[r]);
        op[16 + c] = bf16u(o1[r]);
        if (c < 8) op[32 + c] = bf16u(o2[r]);
        if (c == 0) lpart[pb + q] = l;
    }
}

// ---------------- Cross-attention (M=77) ----------------
__global__ __launch_bounds__(256) void attn_cross2_k(const u16* __restrict__ q, const float* __restrict__ kc,
                                                     const float* __restrict__ vc, u16* __restrict__ out) {
    __shared__ float Pl[4][128];
    const int t = threadIdx.x, w = t >> 6, l = t & 63;
    const int gw = blockIdx.x * 4 + w;
    const int row = gw >> 3, hd = gw & 7;
    const float scale = 0.15811388300841897f;
    float qv[40];
    {
        const u16* qp = q + (size_t)row * DMODEL + hd * DHEAD;
#pragma unroll
        for (int i = 0; i < 5; ++i) {
            s8v v8 = *(const s8v*)(qp + i * 8);
#pragma unroll
            for (int j = 0; j < 8; ++j) qv[i * 8 + j] = b2f((u16)v8[j]) * scale;
        }
    }
    float s1 = -1e30f, s2 = -1e30f;
    if (l < CTXN) {
        const float* kp = kc + (size_t)l * DMODEL + hd * DHEAD;
        float s = 0.f;
#pragma unroll
        for (int i = 0; i < 40; ++i) s += qv[i] * kp[i];
        s1 = s;
    }
    if (l + 64 < CTXN) {
        const float* kp = kc + (size_t)(l + 64) * DMODEL + hd * DHEAD;
        float s = 0.f;
#pragma unroll
        for (int i = 0; i < 40; ++i) s += qv[i] * kp[i];
        s2 = s;
    }
    float mx = fmaxf(s1, s2);
    for (int o = 32; o > 0; o >>= 1) mx = fmaxf(mx, __shfl_xor(mx, o));
    float p1 = (l < CTXN) ? __expf(s1 - mx) : 0.f;
    float p2 = (l + 64 < CTXN) ? __expf(s2 - mx) : 0.f;
    float ps = p1 + p2;
    for (int o = 32; o > 0; o >>= 1) ps += __shfl_xor(ps, o);
    Pl[w][l] = p1;
    Pl[w][l + 64] = p2;
    if (l < DHEAD) {
        float acc = 0.f;
        for (int j = 0; j < CTXN; ++j) acc += Pl[w][j] * vc[(size_t)j * DMODEL + hd * DHEAD + l];
        out[(size_t)row * DMODEL + hd * DHEAD + l] = bf16u(acc / ps);
    }
}

extern "C" void kernel_launch(void* const* d_in, const int* in_sizes, int n_in,
                              void* d_out, int out_size, void* d_ws, size_t ws_size,
                              hipStream_t stream) {
    const float* x      = (const float*)d_in[0];
    const float* ctx    = (const float*)d_in[1];
    const float* gn_w   = (const float*)d_in[2];
    const float* gn_b   = (const float*)d_in[3];
    const float* pin_w  = (const float*)d_in[4];
    const float* pin_b  = (const float*)d_in[5];
    const float* ln1_w  = (const float*)d_in[6];
    const float* ln1_b  = (const float*)d_in[7];
    const float* q1     = (const float*)d_in[8];
    const float* k1     = (const float*)d_in[9];
    const float* v1     = (const float*)d_in[10];
    const float* o1_w   = (const float*)d_in[11];
    const float* o1_b   = (const float*)d_in[12];
    const float* ln2_w  = (const float*)d_in[13];
    const float* ln2_b  = (const float*)d_in[14];
    const float* q2     = (const float*)d_in[15];
    const float* k2     = (const float*)d_in[16];
    const float* v2     = (const float*)d_in[17];
    const float* o2_w   = (const float*)d_in[18];
    const float* o2_b   = (const float*)d_in[19];
    const float* ln3_w  = (const float*)d_in[20];
    const float* ln3_b  = (const float*)d_in[21];
    const float* ff1_w  = (const float*)d_in[22];
    const float* ff1_b  = (const float*)d_in[23];
    const float* ff2_w  = (const float*)d_in[24];
    const float* ff2_b  = (const float*)d_in[25];
    const float* pout_w = (const float*)d_in[26];
    const float* pout_b = (const float*)d_in[27];
    float* out = (float*)d_out;

    char* base = (char*)d_ws;
    float* h     = (float*)(base);                        //  0 .. 5.24 MB
    u16*   qb16  = (u16*)(base + 5242880);
    u16*   kb16  = (u16*)(base + 7864320);
    u16*   vt16  = (u16*)(base + 10485760);               // [320][4096]
    u16*   ao16  = (u16*)(base + 13107200);
    u16*   ffg16 = (u16*)(base + 5242880);                // FF alias
    u16*   wbase = (u16*)(base + 15728640);
    u16* pinT  = wbase;
    u16* q1T   = pinT  + 102400;
    u16* k1T   = q1T   + 102400;
    u16* v1T   = k1T   + 102400;
    u16* o1T   = v1T   + 102400;
    u16* q2T   = o1T   + 102400;
    u16* o2T   = q2T   + 102400;
    u16* k2T   = o2T   + 102400;
    u16* v2T   = k2T   + 245760;
    u16* ff1T  = v2T   + 245760;
    u16* ff2T  = ff1T  + 819200;
    u16* poutT = ff2T  + 409600;                          // ends 20,807,680
    float* lnmu = (float*)(base + 20807680);              // 4096
    float* lnrs = lnmu + 4096;
    float* k2f  = lnrs + 4096;                            // 77*320 pad 25600
    float* v2f  = k2f + 25600;
    u16*   Opart = (u16*)(v2f + 25600);                   // 2*8*4096*40 bf16 = 5.24 MB
    float* lpart = (float*)(Opart + (size_t)2 * 8 * 4096 * 40);
    float* gnsc  = lpart + 2 * 8 * 4096;
    float* gnsh  = gnsc + 320;

    // 0. weights -> bf16 [O][K] via coalesced tiled transpose
    WCs wd;
    wd.a[0]  = {pin_w,  pinT,  320,  320,  0};
    wd.a[1]  = {q1,     q1T,   320,  320,  1};
    wd.a[2]  = {k1,     k1T,   320,  320,  1};
    wd.a[3]  = {v1,     v1T,   320,  320,  1};
    wd.a[4]  = {o1_w,   o1T,   320,  320,  1};
    wd.a[5]  = {q2,     q2T,   320,  320,  1};
    wd.a[6]  = {o2_w,   o2T,   320,  320,  1};
    wd.a[7]  = {k2,     k2T,   768,  320,  1};
    wd.a[8]  = {v2,     v2T,   768,  320,  1};
    wd.a[9]  = {ff1_w,  ff1T,  320,  2560, 1};
    wd.a[10] = {ff2_w,  ff2T,  1280, 320,  1};
    wd.a[11] = {pout_w, poutT, 320,  320,  0};
    wcast2_k<<<dim3(800, 12), 256, 0, stream>>>(wd);

    GArg gz = {nullptr, nullptr, nullptr, nullptr, 0};

    // 1. GN stats; proj_in (GN fused in staging)
    gn_stats_k<<<32, 256, 0, stream>>>(x, gn_w, gn_b, gnsc, gnsh);
    {
        GArg g0 = {pinT, pin_b, h, nullptr, 0};
        gemm_t<0><<<dim3(5, 64, 1), 256, 0, stream>>>(x, 2, 4096, nullptr, nullptr, gnsc, gnsh,
                                                      g0, gz, gz, nullptr, 4096, 320, 320, 0);
    }
    // 2. qkv fused (LN1 in staging)
    ln_stats_k<<<1024, 256, 0, stream>>>(h, lnmu, lnrs);
    {
        GArg g0 = {q1T, nullptr, nullptr, qb16, 4};
        GArg g1 = {nullptr, nullptr, nullptr, kb16, 0};
        GArg g2 = {nullptr, nullptr, nullptr, vt16, 0};
        gemm_t<1><<<dim3(15, 64, 1), 256, 0, stream>>>(h, 3, 320, lnmu, lnrs, ln1_w, ln1_b,
                                                       g0, g1, g2, nullptr, 4096, 320, 960, 4096);
    }
    attn_self5_k<<<dim3(64, 8, 2), 256, 0, stream>>>(qb16, kb16, vt16, Opart, lpart);
    // 3. o1 proj: A = combined 2-split partials, residual h
    {
        GArg g0 = {o1T, o1_b, h, nullptr, 0};
        gemm_t<2><<<dim3(5, 64, 1), 256, 0, stream>>>(Opart, 4, 0, lpart, nullptr, nullptr, nullptr,
                                                      g0, gz, gz, h, 4096, 320, 320, 0);
    }
    // 4. cross-attention block (LN2 in q2 staging)
    ln_stats_k<<<1024, 256, 0, stream>>>(h, lnmu, lnrs);
    {
        GArg g0 = {q2T, nullptr, nullptr, qb16, 1};
        gemm_t<3><<<dim3(5, 64, 1), 256, 0, stream>>>(h, 3, 320, lnmu, lnrs, ln2_w, ln2_b,
                                                      g0, gz, gz, nullptr, 4096, 320, 320, 0);
    }
    {
        GArg g0 = {k2T, nullptr, k2f, nullptr, 0};
        GArg g1 = {v2T, nullptr, v2f, nullptr, 0};
        gemm_t<4><<<dim3(5, 2, 2), 256, 0, stream>>>(ctx, 1, 768, nullptr, nullptr, nullptr, nullptr,
                                                     g0, g1, gz, nullptr, 77, 768, 320, 0);
    }
    attn_cross2_k<<<8192, 256, 0, stream>>>(qb16, k2f, v2f, ao16);
    {
        GArg g0 = {o2T, o2_b, h, nullptr, 0};
        gemm_t<5><<<dim3(5, 64, 1), 256, 0, stream>>>(ao16, 0, 320, nullptr, nullptr, nullptr, nullptr,
                                                      g0, gz, gz, h, 4096, 320, 320, 0);
    }
    // 5. GEGLU FF (LN3 in ff1 staging)
    ln_stats_k<<<1024, 256, 0, stream>>>(h, lnmu, lnrs);
    gemm_gg<<<dim3(20, 64, 1), 256, 0, stream>>>(h, 320, lnmu, lnrs, ln3_w, ln3_b,
                                                 ff1T, ff1_b, ffg16, 320, 1280, 1280);
    {
        GArg g0 = {ff2T, ff2_b, h, nullptr, 0};
        gemm_t<6><<<dim3(5, 64, 1), 256, 0, stream>>>(ffg16, 0, 1280, nullptr, nullptr, nullptr, nullptr,
                                                      g0, gz, gz, h, 4096, 1280, 320, 0);
    }
    // 6. proj_out + input residual
    {
        GArg g0 = {poutT, pout_b, out, nullptr, 3};
        gemm_t<7><<<dim3(5, 64, 1), 256, 0, stream>>>(h, 1, 320, nullptr, nullptr, nullptr, nullptr,
                                                      g0, gz, gz, x, 4096, 320, 320, 4096);
    }
}

// Round 11
// 513.082 us; speedup vs baseline: 1.2313x; 1.0839x over previous
//
#include <hip/hip_runtime.h>
#include <hip/hip_bf16.h>
#include <math.h>

#define N_SEQ  4096
#define DMODEL 320
#define NHEADS 8
#define DHEAD  40
#define CTXN   77
#define CTXD   768
#define FFI    1280

typedef short s8v __attribute__((ext_vector_type(8)));
typedef short s4v __attribute__((ext_vector_type(4)));
typedef float f4v __attribute__((ext_vector_type(4)));
typedef unsigned short u16;

static __device__ __forceinline__ u16 bf16u(float x) {           // RNE
    unsigned u = __float_as_uint(x);
    return (u16)((u + 0x7FFFu + ((u >> 16) & 1u)) >> 16);
}
static __device__ __forceinline__ float b2f(u16 v) { return __uint_as_float((unsigned)v << 16); }
static __device__ __forceinline__ unsigned pack2(float a, float b) {
    return (unsigned)bf16u(a) | ((unsigned)bf16u(b) << 16);
}

// ---------------- weight pre-convert v2: coalesced tiled transpose ----------------
struct WC { const float* s; u16* d; int K, O, trans; };
struct WCs { WC a[12]; };
__global__ __launch_bounds__(256) void wcast2_k(WCs P) {
    __shared__ float tile[32][33];
    WC w = P.a[blockIdx.y];
    if (w.trans) {
        int ntk = w.K >> 5, nto = w.O >> 5;
        int tid = blockIdx.x;
        if (tid >= ntk * nto) return;
        int tk = tid % ntk, to = tid / ntk;
        int lr = threadIdx.x >> 5, lc = threadIdx.x & 31;
#pragma unroll
        for (int p = 0; p < 4; ++p) {
            int k = tk * 32 + p * 8 + lr;
            tile[p * 8 + lr][lc] = w.s[(size_t)k * w.O + to * 32 + lc];
        }
        __syncthreads();
#pragma unroll
        for (int p = 0; p < 4; ++p) {
            int o = to * 32 + p * 8 + lr;
            w.d[(size_t)o * w.K + tk * 32 + lc] = bf16u(tile[lc][p * 8 + lr]);
        }
    } else {
        int nel = w.K * w.O;
        for (int e = blockIdx.x * 256 + threadIdx.x; e < nel; e += gridDim.x * 256)
            w.d[e] = bf16u(w.s[e]);
    }
}

// ---------------- GroupNorm stats -> per-channel scale/shift ----------------
__global__ __launch_bounds__(256) void gn_stats_k(const float* __restrict__ x,
                                                  const float* __restrict__ gw, const float* __restrict__ gb,
                                                  float* __restrict__ sc, float* __restrict__ sh) {
    __shared__ float red[512];
    __shared__ float ms[2];
    int g = blockIdx.x, t = threadIdx.x;
    const float* xp = x + (size_t)g * 40960;
    float s = 0.f, ss = 0.f;
    for (int i = t; i < 40960; i += 256) { float v = xp[i]; s += v; ss += v * v; }
    red[t] = s; red[256 + t] = ss;
    __syncthreads();
    for (int st = 128; st > 0; st >>= 1) {
        if (t < st) { red[t] += red[t + st]; red[256 + t] += red[256 + t + st]; }
        __syncthreads();
    }
    if (t == 0) {
        float mean = red[0] / 40960.f;
        float var  = red[256] / 40960.f - mean * mean;
        ms[0] = mean; ms[1] = rsqrtf(var + 1e-6f);
    }
    __syncthreads();
    if (t < 10) {
        int c = g * 10 + t;
        float scv = gw[c] * ms[1];
        sc[c] = scv;
        sh[c] = gb[c] - ms[0] * scv;
    }
}

// ---------------- LayerNorm stats ----------------
__global__ __launch_bounds__(256) void ln_stats_k(const float* __restrict__ in,
                                                  float* __restrict__ mu, float* __restrict__ rs) {
    int row = blockIdx.x * 4 + (threadIdx.x >> 6), l = threadIdx.x & 63;
    const float* p = in + (size_t)row * DMODEL;
    float s = 0.f, ss = 0.f;
#pragma unroll
    for (int j = 0; j < 5; ++j) { float v = p[l + 64 * j]; s += v; ss += v * v; }
    for (int o = 32; o > 0; o >>= 1) { s += __shfl_xor(s, o); ss += __shfl_xor(ss, o); }
    if (l == 0) {
        float mean = s * (1.f / 320.f);
        float var  = ss * (1.f / 320.f) - mean * mean;
        mu[row] = mean;
        rs[row] = rsqrtf(var + 1e-5f);
    }
}

struct GArg { const u16* Wt; const float* bias; float* outf; u16* outb; int ob_mode; };
#define GP 72

// ---------------- gemm_t<SITE>: 64x64 tile, K-chunk 64, REGISTER-PREFETCH pipeline ----------------
// A modes: 0 bf16 row-major | 1 f32 row-major | 2 f32 col-major + GN coef | 3 f32 row-major + LN
//          4 attention 2-split combine (Av=Opart bf16, mu=lpart)
// ob_mode: 0 outf f32 row-major | 1 outb bf16 row-major | 2 outb bf16 transposed
//          3 outf f32 transposed + res[o][n] | 4 qkv split
template<int SITE>
__global__ __launch_bounds__(256) void gemm_t(const void* __restrict__ Av, int a_mode, int lda,
                                              const float* __restrict__ mu, const float* __restrict__ rs,
                                              const float* __restrict__ cw, const float* __restrict__ cb,
                                              GArg g0, GArg g1, GArg g2,
                                              const float* __restrict__ res,
                                              int Mrows, int K, int Oout, int obT_stride) {
    __shared__ __align__(16) u16 As[64 * GP];
    __shared__ __align__(16) u16 Wsm[64 * GP];
    const int t = threadIdx.x;
    const int w = t >> 6, lane = t & 63, c = lane & 15, quad = lane >> 4;
    const int o0 = blockIdx.x * 64, n0 = blockIdx.y * 64;
    GArg g = (blockIdx.z == 0) ? g0 : ((blockIdx.z == 1) ? g1 : g2);
    const f4v zero = {0.f, 0.f, 0.f, 0.f};
    f4v acc[4] = {zero, zero, zero, zero};
    const s8v z8 = {0, 0, 0, 0, 0, 0, 0, 0};
    const int nk = K >> 6;

    // prefetch registers
    float fA[16];
    s8v bA0 = z8, bA1 = z8;
    s8v wv0, wv1;

    // ---- per-chunk load (global -> regs) ----
    auto loadW = [&](int k0) {
        int i0 = t, i1 = t + 256;
        wv0 = *(const s8v*)(g.Wt + (size_t)(o0 + (i0 >> 3)) * K + k0 + (i0 & 7) * 8);
        wv1 = *(const s8v*)(g.Wt + (size_t)(o0 + (i1 >> 3)) * K + k0 + (i1 & 7) * 8);
    };
    auto storeW = [&]() {
        int i0 = t, i1 = t + 256;
        *(s8v*)&Wsm[(i0 >> 3) * GP + (i0 & 7) * 8] = wv0;
        *(s8v*)&Wsm[(i1 >> 3) * GP + (i1 & 7) * 8] = wv1;
    };
    auto loadA = [&](int k0) {
        if (a_mode == 0) {
            const u16* A = (const u16*)Av;
            int i0 = t, i1 = t + 256;
            int nA = n0 + (i0 >> 3), nB = n0 + (i1 >> 3);
            bA0 = (nA < Mrows) ? *(const s8v*)(A + (size_t)nA * lda + k0 + (i0 & 7) * 8) : z8;
            bA1 = (nB < Mrows) ? *(const s8v*)(A + (size_t)nB * lda + k0 + (i1 & 7) * 8) : z8;
        } else if (a_mode == 1) {
            const float* A = (const float*)Av;
            int r = t >> 2, s16 = (t & 3) * 16;
            int n = n0 + r;
            if (n < Mrows) {
                const float* src = A + (size_t)n * lda + k0 + s16;
#pragma unroll
                for (int i = 0; i < 16; ++i) fA[i] = src[i];
            } else {
#pragma unroll
                for (int i = 0; i < 16; ++i) fA[i] = 0.f;
            }
        } else if (a_mode == 2) {
            const float* A = (const float*)Av;
#pragma unroll
            for (int j = 0; j < 16; ++j) {
                int e = t + 256 * j; int nn = e & 63, kk = e >> 6;
                int n = n0 + nn, kgl = k0 + kk;
                fA[j] = (n < Mrows) ? A[(size_t)kgl * lda + n] * cw[kgl] + cb[kgl] : 0.f;
            }
        } else if (a_mode == 3) {
            const float* A = (const float*)Av;
            int r = t >> 2, s16 = (t & 3) * 16;
            int n = n0 + r;
            if (n < Mrows) {
                const float* src = A + (size_t)n * lda + k0 + s16;
                const float* cwp = cw + k0 + s16;
                const float* cbp = cb + k0 + s16;
                float m_ = mu[n], rr = rs[n];
#pragma unroll
                for (int i = 0; i < 16; ++i) fA[i] = (src[i] - m_) * rr * cwp[i] + cbp[i];
            } else {
#pragma unroll
                for (int i = 0; i < 16; ++i) fA[i] = 0.f;
            }
        } else {   // 4: 2-split attention combine
            const u16* Op = (const u16*)Av;
            const float* lp = mu;
            int r = t >> 2, s16 = (t & 3) * 16;
            int n = n0 + r;
            int ch0 = k0 + s16;
            int hdA = ch0 / 40;
            int hdB = (ch0 + 15) / 40;
            float invA = 1.f / (lp[(size_t)hdA * N_SEQ + n] + lp[(size_t)(8 + hdA) * N_SEQ + n]);
            float invB = (hdB == hdA) ? invA
                       : 1.f / (lp[(size_t)hdB * N_SEQ + n] + lp[(size_t)(8 + hdB) * N_SEQ + n]);
#pragma unroll
            for (int i = 0; i < 16; ++i) {
                int ch = ch0 + i;
                int hd = ch / 40;
                int d  = ch - hd * 40;
                float num = b2f(Op[((size_t)hd * N_SEQ + n) * DHEAD + d])
                          + b2f(Op[((size_t)(8 + hd) * N_SEQ + n) * DHEAD + d]);
                fA[i] = num * ((hd == hdA) ? invA : invB);
            }
        }
    };
    auto storeA = [&](int k0) {
        if (a_mode == 0) {
            int i0 = t, i1 = t + 256;
            *(s8v*)&As[(i0 >> 3) * GP + (i0 & 7) * 8] = bA0;
            *(s8v*)&As[(i1 >> 3) * GP + (i1 & 7) * 8] = bA1;
        } else if (a_mode == 2) {
#pragma unroll
            for (int j = 0; j < 16; ++j) {
                int e = t + 256 * j; int nn = e & 63, kk = e >> 6;
                As[nn * GP + kk] = bf16u(fA[j]);
            }
        } else {   // modes 1,3,4: row-major packed
            int r = t >> 2, s16 = (t & 3) * 16;
            unsigned* dst = (unsigned*)&As[r * GP + s16];
#pragma unroll
            for (int i = 0; i < 8; ++i) dst[i] = pack2(fA[2 * i], fA[2 * i + 1]);
        }
    };

    // ---- pipeline: stage chunk 0, then overlap loads of k+1 with MFMAs of k ----
    loadA(0); loadW(0);
    storeA(0); storeW();
    __syncthreads();
    for (int k = 0; k < nk; ++k) {
        if (k + 1 < nk) { loadA((k + 1) << 6); loadW((k + 1) << 6); }
        s8v a0 = *(const s8v*)&As[(w * 16 + c) * GP + quad * 8];
        s8v a1 = *(const s8v*)&As[(w * 16 + c) * GP + 32 + quad * 8];
#pragma unroll
        for (int nt = 0; nt < 4; ++nt) {
            s8v b0 = *(const s8v*)&Wsm[(nt * 16 + c) * GP + quad * 8];
            s8v b1 = *(const s8v*)&Wsm[(nt * 16 + c) * GP + 32 + quad * 8];
            acc[nt] = __builtin_amdgcn_mfma_f32_16x16x32_bf16(a0, b0, acc[nt], 0, 0, 0);
            acc[nt] = __builtin_amdgcn_mfma_f32_16x16x32_bf16(a1, b1, acc[nt], 0, 0, 0);
        }
        __syncthreads();
        if (k + 1 < nk) {
            storeA((k + 1) << 6); storeW();
            __syncthreads();
        }
    }
    // ---------- epilogue ----------
#pragma unroll
    for (int nt = 0; nt < 4; ++nt) {
        int o = o0 + nt * 16 + c;
        float vv[4];
#pragma unroll
        for (int r = 0; r < 4; ++r) vv[r] = acc[nt][r] + (g.bias ? g.bias[o] : 0.f);
        if (g.ob_mode == 3) {
            int nb = n0 + w * 16 + quad * 4;
            const float4 x4 = *(const float4*)(res + (size_t)o * obT_stride + nb);
            float4 o4 = make_float4(vv[0] + x4.x, vv[1] + x4.y, vv[2] + x4.z, vv[3] + x4.w);
            *(float4*)(g.outf + (size_t)o * obT_stride + nb) = o4;
        } else if (g.ob_mode == 4) {
#pragma unroll
            for (int r = 0; r < 4; ++r) {
                int n = n0 + w * 16 + quad * 4 + r;
                u16 bv = bf16u(vv[r]);
                if (o < 320)      g0.outb[(size_t)n * 320 + o] = bv;
                else if (o < 640) g1.outb[(size_t)n * 320 + (o - 320)] = bv;
                else              g2.outb[(size_t)(o - 640) * obT_stride + n] = bv;
            }
        } else {
#pragma unroll
            for (int r = 0; r < 4; ++r) {
                int n = n0 + w * 16 + quad * 4 + r;
                if (n >= Mrows) continue;
                float v = vv[r];
                if (res) v += res[(size_t)n * Oout + o];
                if (g.outf) g.outf[(size_t)n * Oout + o] = v;
                if (g.ob_mode == 1) g.outb[(size_t)n * Oout + o] = bf16u(v);
                else if (g.ob_mode == 2) g.outb[(size_t)o * obT_stride + n] = bf16u(v);
            }
        }
    }
}

// ---------------- gemm_gg: ff1 GEGLU (LN staging), register-prefetch pipeline ----------------
__global__ __launch_bounds__(256) void gemm_gg(const float* __restrict__ A, int lda,
                                               const float* __restrict__ mu, const float* __restrict__ rs,
                                               const float* __restrict__ cw, const float* __restrict__ cb,
                                               const u16* __restrict__ Wt, const float* __restrict__ bias,
                                               u16* __restrict__ outb,
                                               int K, int Oout, int geglu_off) {
    __shared__ __align__(16) u16 As[64 * GP];
    __shared__ __align__(16) u16 Wsm[64 * GP];
    __shared__ __align__(16) u16 Wgm[64 * GP];
    const int t = threadIdx.x;
    const int w = t >> 6, lane = t & 63, c = lane & 15, quad = lane >> 4;
    const int o0 = blockIdx.x * 64, n0 = blockIdx.y * 64;
    const f4v zero = {0.f, 0.f, 0.f, 0.f};
    f4v acc[4]  = {zero, zero, zero, zero};
    f4v accg[4] = {zero, zero, zero, zero};
    const int nk = K >> 6;

    float fA[16];
    s8v wv0, wv1, gv0, gv1;

    auto loadWG = [&](int k0) {
        int i0 = t, i1 = t + 256;
        wv0 = *(const s8v*)(Wt + (size_t)(o0 + (i0 >> 3)) * K + k0 + (i0 & 7) * 8);
        wv1 = *(const s8v*)(Wt + (size_t)(o0 + (i1 >> 3)) * K + k0 + (i1 & 7) * 8);
        gv0 = *(const s8v*)(Wt + (size_t)(o0 + (i0 >> 3) + geglu_off) * K + k0 + (i0 & 7) * 8);
        gv1 = *(const s8v*)(Wt + (size_t)(o0 + (i1 >> 3) + geglu_off) * K + k0 + (i1 & 7) * 8);
    };
    auto storeWG = [&]() {
        int i0 = t, i1 = t + 256;
        *(s8v*)&Wsm[(i0 >> 3) * GP + (i0 & 7) * 8] = wv0;
        *(s8v*)&Wsm[(i1 >> 3) * GP + (i1 & 7) * 8] = wv1;
        *(s8v*)&Wgm[(i0 >> 3) * GP + (i0 & 7) * 8] = gv0;
        *(s8v*)&Wgm[(i1 >> 3) * GP + (i1 & 7) * 8] = gv1;
    };
    auto loadA = [&](int k0) {
        int r = t >> 2, s16 = (t & 3) * 16;
        int n = n0 + r;
        const float* src = A + (size_t)n * lda + k0 + s16;
        const float* cwp = cw + k0 + s16;
        const float* cbp = cb + k0 + s16;
        float m_ = mu[n], rr = rs[n];
#pragma unroll
        for (int i = 0; i < 16; ++i) fA[i] = (src[i] - m_) * rr * cwp[i] + cbp[i];
    };
    auto storeA = [&]() {
        int r = t >> 2, s16 = (t & 3) * 16;
        unsigned* dst = (unsigned*)&As[r * GP + s16];
#pragma unroll
        for (int i = 0; i < 8; ++i) dst[i] = pack2(fA[2 * i], fA[2 * i + 1]);
    };

    loadA(0); loadWG(0);
    storeA(); storeWG();
    __syncthreads();
    for (int k = 0; k < nk; ++k) {
        if (k + 1 < nk) { loadA((k + 1) << 6); loadWG((k + 1) << 6); }
        s8v a0 = *(const s8v*)&As[(w * 16 + c) * GP + quad * 8];
        s8v a1 = *(const s8v*)&As[(w * 16 + c) * GP + 32 + quad * 8];
#pragma unroll
        for (int nt = 0; nt < 4; ++nt) {
            s8v b0 = *(const s8v*)&Wsm[(nt * 16 + c) * GP + quad * 8];
            s8v b1 = *(const s8v*)&Wsm[(nt * 16 + c) * GP + 32 + quad * 8];
            acc[nt] = __builtin_amdgcn_mfma_f32_16x16x32_bf16(a0, b0, acc[nt], 0, 0, 0);
            acc[nt] = __builtin_amdgcn_mfma_f32_16x16x32_bf16(a1, b1, acc[nt], 0, 0, 0);
            s8v q0 = *(const s8v*)&Wgm[(nt * 16 + c) * GP + quad * 8];
            s8v q1 = *(const s8v*)&Wgm[(nt * 16 + c) * GP + 32 + quad * 8];
            accg[nt] = __builtin_amdgcn_mfma_f32_16x16x32_bf16(a0, q0, accg[nt], 0, 0, 0);
            accg[nt] = __builtin_amdgcn_mfma_f32_16x16x32_bf16(a1, q1, accg[nt], 0, 0, 0);
        }
        __syncthreads();
        if (k + 1 < nk) {
            storeA(); storeWG();
            __syncthreads();
        }
    }
#pragma unroll
    for (int nt = 0; nt < 4; ++nt) {
        int o = o0 + nt * 16 + c;
#pragma unroll
        for (int r = 0; r < 4; ++r) {
            int n = n0 + w * 16 + quad * 4 + r;
            float v = acc[nt][r] + bias[o];
            float gg = accg[nt][r] + bias[o + geglu_off];
            v = v * 0.5f * gg * (1.f + erff(gg * 0.70710678118654752f));
            outb[(size_t)n * Oout + o] = bf16u(v);
        }
    }
}

// ---------------- Self-attention v5 (R8/R10 proven): 2-split, 31KB LDS ----------------
#define KSP 40
#define PSP 140
#define VP  136
__global__ __launch_bounds__(256) void attn_self5_k(const u16* __restrict__ qb, const u16* __restrict__ kb,
                                                    const u16* __restrict__ vt,
                                                    u16* __restrict__ Opart, float* __restrict__ lpart) {
    __shared__ __align__(16) u16 KsPs[64 * PSP];
    __shared__ __align__(16) u16 Vs[48 * VP];
    const int t = threadIdx.x;
    const int w = t >> 6, lane = t & 63, c = lane & 15, quad = lane >> 4;
    const int hd = blockIdx.y, ks = blockIdx.z;
    const int q0 = blockIdx.x * 64;
    const float SC2 = 0.15811388300841897f * 1.4426950408889634f;
    const f4v zero = {0.f, 0.f, 0.f, 0.f};
    const s8v z8 = {0, 0, 0, 0, 0, 0, 0, 0};

    for (int i = t; i < 8 * VP / 2; i += 256) ((unsigned*)&Vs[40 * VP])[i] = 0u;

    const u16* qrow = qb + (size_t)(q0 + w * 16 + c) * DMODEL + hd * DHEAD;
    s8v qa0 = *(const s8v*)(qrow + quad * 8);
    s8v qa1 = z8;
    if (quad == 0) qa1 = *(const s8v*)(qrow + 32);

    float lacc[4] = {0.f, 0.f, 0.f, 0.f};
    f4v o0 = zero, o1 = zero, o2 = zero;

    for (int kt = 0; kt < 16; ++kt) {
        const int k0 = ks * 2048 + kt * 128;
        __syncthreads();
        for (int i = t; i < 640; i += 256) {
            int r = i / 5, sg = i - r * 5;
            *(s8v*)&KsPs[r * KSP + sg * 8] = *(const s8v*)(kb + (size_t)(k0 + r) * DMODEL + hd * DHEAD + sg * 8);
        }
        for (int i = t; i < 640; i += 256) {
            int d = i >> 4, sg = i & 15;
            *(s8v*)&Vs[d * VP + sg * 8] = *(const s8v*)(vt + (size_t)(hd * DHEAD + d) * N_SEQ + k0 + sg * 8);
        }
        __syncthreads();

        f4v sarr[8];
#pragma unroll
        for (int nt = 0; nt < 8; ++nt) {
            const int kr = nt * 16 + c;
            s8v b0 = *(const s8v*)&KsPs[kr * KSP + quad * 8];
            s8v b1 = z8;
            if (quad == 0) b1 = *(const s8v*)&KsPs[kr * KSP + 32];
            f4v s = __builtin_amdgcn_mfma_f32_16x16x32_bf16(qa0, b0, zero, 0, 0, 0);
            s = __builtin_amdgcn_mfma_f32_16x16x32_bf16(qa1, b1, s, 0, 0, 0);
            sarr[nt] = s;
        }
        __syncthreads();

        u16* psw = &KsPs[(size_t)(w * 16 + quad * 4) * PSP + c];
#pragma unroll
        for (int reg = 0; reg < 8; ++reg) {
            const int colb = (reg >> 2) * 64 + (reg & 3) * 16;
#pragma unroll
            for (int r = 0; r < 4; ++r) {
                float pv = exp2f(sarr[reg][r] * SC2);
                lacc[r] += pv;
                psw[r * PSP + colb] = (u16)((__float_as_uint(pv) + 0x8000u) >> 16);
            }
        }

        const u16* prow = &KsPs[(size_t)(w * 16 + c) * PSP];
#pragma unroll
        for (int h2 = 0; h2 < 2; ++h2) {
            s8v pa0, pa1;
            {
                s4v lo = *(const s4v*)(prow + h2 * 64 + quad * 8);
                s4v hi = *(const s4v*)(prow + h2 * 64 + quad * 8 + 4);
                pa0 = (s8v){lo[0], lo[1], lo[2], lo[3], hi[0], hi[1], hi[2], hi[3]};
                s4v lo2 = *(const s4v*)(prow + h2 * 64 + 32 + quad * 8);
                s4v hi2 = *(const s4v*)(prow + h2 * 64 + 32 + quad * 8 + 4);
                pa1 = (s8v){lo2[0], lo2[1], lo2[2], lo2[3], hi2[0], hi2[1], hi2[2], hi2[3]};
            }
            {
                s8v v0 = *(const s8v*)&Vs[(0 * 16 + c) * VP + h2 * 64 + quad * 8];
                s8v v1 = *(const s8v*)&Vs[(0 * 16 + c) * VP + h2 * 64 + 32 + quad * 8];
                o0 = __builtin_amdgcn_mfma_f32_16x16x32_bf16(pa0, v0, o0, 0, 0, 0);
                o0 = __builtin_amdgcn_mfma_f32_16x16x32_bf16(pa1, v1, o0, 0, 0, 0);
            }
            {
                s8v v0 = *(const s8v*)&Vs[(1 * 16 + c) * VP + h2 * 64 + quad * 8];
                s8v v1 = *(const s8v*)&Vs[(1 * 16 + c) * VP + h2 * 64 + 32 + quad * 8];
                o1 = __builtin_amdgcn_mfma_f32_16x16x32_bf16(pa0, v0, o1, 0, 0, 0);
                o1 = __builtin_amdgcn_mfma_f32_16x16x32_bf16(pa1, v1, o1, 0, 0, 0);
            }
            {
                s8v v0 = *(const s8v*)&Vs[(2 * 16 + c) * VP + h2 * 64 + quad * 8];
                s8v v1 = *(const s8v*)&Vs[(2 * 16 + c) * VP + h2 * 64 + 32 + quad * 8];
                o2 = __builtin_amdgcn_mfma_f32_16x16x32_bf16(pa0, v0, o2, 0, 0, 0);
                o2 = __builtin_amdgcn_mfma_f32_16x16x32_bf16(pa1, v1, o2, 0, 0, 0);
            }
        }
    }

    const size_t pb = (size_t)(ks * 8 + hd) * N_SEQ;
#pragma unroll
    for (int r = 0; r < 4; ++r) {
        float l = lacc[r];
        l += __shfl_xor(l, 1); l += __shfl_xor(l, 2); l += __shfl_xor(l, 4); l += __shfl_xor(l, 8);
        int q = q0 + w * 16 + quad * 4 + r;
        u16* op = Opart + (pb + q) * DHEAD;
        op[c]      = bf16u(o0[r]);
        op[16 + c] = bf16u(o1[r]);
        if (c < 8) op[32 + c] = bf16u(o2[r]);
        if (c == 0) lpart[pb + q] = l;
    }
}

// ---------------- Cross-attention (M=77) ----------------
__global__ __launch_bounds__(256) void attn_cross2_k(const u16* __restrict__ q, const float* __restrict__ kc,
                                                     const float* __restrict__ vc, u16* __restrict__ out) {
    __shared__ float Pl[4][128];
    const int t = threadIdx.x, w = t >> 6, l = t & 63;
    const int gw = blockIdx.x * 4 + w;
    const int row = gw >> 3, hd = gw & 7;
    const float scale = 0.15811388300841897f;
    float qv[40];
    {
        const u16* qp = q + (size_t)row * DMODEL + hd * DHEAD;
#pragma unroll
        for (int i = 0; i < 5; ++i) {
            s8v v8 = *(const s8v*)(qp + i * 8);
#pragma unroll
            for (int j = 0; j < 8; ++j) qv[i * 8 + j] = b2f((u16)v8[j]) * scale;
        }
    }
    float s1 = -1e30f, s2 = -1e30f;
    if (l < CTXN) {
        const float* kp = kc + (size_t)l * DMODEL + hd * DHEAD;
        float s = 0.f;
#pragma unroll
        for (int i = 0; i < 40; ++i) s += qv[i] * kp[i];
        s1 = s;
    }
    if (l + 64 < CTXN) {
        const float* kp = kc + (size_t)(l + 64) * DMODEL + hd * DHEAD;
        float s = 0.f;
#pragma unroll
        for (int i = 0; i < 40; ++i) s += qv[i] * kp[i];
        s2 = s;
    }
    float mx = fmaxf(s1, s2);
    for (int o = 32; o > 0; o >>= 1) mx = fmaxf(mx, __shfl_xor(mx, o));
    float p1 = (l < CTXN) ? __expf(s1 - mx) : 0.f;
    float p2 = (l + 64 < CTXN) ? __expf(s2 - mx) : 0.f;
    float ps = p1 + p2;
    for (int o = 32; o > 0; o >>= 1) ps += __shfl_xor(ps, o);
    Pl[w][l] = p1;
    Pl[w][l + 64] = p2;
    if (l < DHEAD) {
        float acc = 0.f;
        for (int j = 0; j < CTXN; ++j) acc += Pl[w][j] * vc[(size_t)j * DMODEL + hd * DHEAD + l];
        out[(size_t)row * DMODEL + hd * DHEAD + l] = bf16u(acc / ps);
    }
}

extern "C" void kernel_launch(void* const* d_in, const int* in_sizes, int n_in,
                              void* d_out, int out_size, void* d_ws, size_t ws_size,
                              hipStream_t stream) {
    const float* x      = (const float*)d_in[0];
    const float* ctx    = (const float*)d_in[1];
    const float* gn_w   = (const float*)d_in[2];
    const float* gn_b   = (const float*)d_in[3];
    const float* pin_w  = (const float*)d_in[4];
    const float* pin_b  = (const float*)d_in[5];
    const float* ln1_w  = (const float*)d_in[6];
    const float* ln1_b  = (const float*)d_in[7];
    const float* q1     = (const float*)d_in[8];
    const float* k1     = (const float*)d_in[9];
    const float* v1     = (const float*)d_in[10];
    const float* o1_w   = (const float*)d_in[11];
    const float* o1_b   = (const float*)d_in[12];
    const float* ln2_w  = (const float*)d_in[13];
    const float* ln2_b  = (const float*)d_in[14];
    const float* q2     = (const float*)d_in[15];
    const float* k2     = (const float*)d_in[16];
    const float* v2     = (const float*)d_in[17];
    const float* o2_w   = (const float*)d_in[18];
    const float* o2_b   = (const float*)d_in[19];
    const float* ln3_w  = (const float*)d_in[20];
    const float* ln3_b  = (const float*)d_in[21];
    const float* ff1_w  = (const float*)d_in[22];
    const float* ff1_b  = (const float*)d_in[23];
    const float* ff2_w  = (const float*)d_in[24];
    const float* ff2_b  = (const float*)d_in[25];
    const float* pout_w = (const float*)d_in[26];
    const float* pout_b = (const float*)d_in[27];
    float* out = (float*)d_out;

    char* base = (char*)d_ws;
    float* h     = (float*)(base);
    u16*   qb16  = (u16*)(base + 5242880);
    u16*   kb16  = (u16*)(base + 7864320);
    u16*   vt16  = (u16*)(base + 10485760);
    u16*   ao16  = (u16*)(base + 13107200);
    u16*   ffg16 = (u16*)(base + 5242880);
    u16*   wbase = (u16*)(base + 15728640);
    u16* pinT  = wbase;
    u16* q1T   = pinT  + 102400;
    u16* k1T   = q1T   + 102400;
    u16* v1T   = k1T   + 102400;
    u16* o1T   = v1T   + 102400;
    u16* q2T   = o1T   + 102400;
    u16* o2T   = q2T   + 102400;
    u16* k2T   = o2T   + 102400;
    u16* v2T   = k2T   + 245760;
    u16* ff1T  = v2T   + 245760;
    u16* ff2T  = ff1T  + 819200;
    u16* poutT = ff2T  + 409600;
    float* lnmu = (float*)(base + 20807680);
    float* lnrs = lnmu + 4096;
    float* k2f  = lnrs + 4096;
    float* v2f  = k2f + 25600;
    u16*   Opart = (u16*)(v2f + 25600);
    float* lpart = (float*)(Opart + (size_t)2 * 8 * 4096 * 40);
    float* gnsc  = lpart + 2 * 8 * 4096;
    float* gnsh  = gnsc + 320;

    WCs wd;
    wd.a[0]  = {pin_w,  pinT,  320,  320,  0};
    wd.a[1]  = {q1,     q1T,   320,  320,  1};
    wd.a[2]  = {k1,     k1T,   320,  320,  1};
    wd.a[3]  = {v1,     v1T,   320,  320,  1};
    wd.a[4]  = {o1_w,   o1T,   320,  320,  1};
    wd.a[5]  = {q2,     q2T,   320,  320,  1};
    wd.a[6]  = {o2_w,   o2T,   320,  320,  1};
    wd.a[7]  = {k2,     k2T,   768,  320,  1};
    wd.a[8]  = {v2,     v2T,   768,  320,  1};
    wd.a[9]  = {ff1_w,  ff1T,  320,  2560, 1};
    wd.a[10] = {ff2_w,  ff2T,  1280, 320,  1};
    wd.a[11] = {pout_w, poutT, 320,  320,  0};
    wcast2_k<<<dim3(800, 12), 256, 0, stream>>>(wd);

    GArg gz = {nullptr, nullptr, nullptr, nullptr, 0};

    // 1. GN stats; proj_in (GN fused in staging)
    gn_stats_k<<<32, 256, 0, stream>>>(x, gn_w, gn_b, gnsc, gnsh);
    {
        GArg g0 = {pinT, pin_b, h, nullptr, 0};
        gemm_t<0><<<dim3(5, 64, 1), 256, 0, stream>>>(x, 2, 4096, nullptr, nullptr, gnsc, gnsh,
                                                      g0, gz, gz, nullptr, 4096, 320, 320, 0);
    }
    // 2. qkv fused (LN1 in staging)
    ln_stats_k<<<1024, 256, 0, stream>>>(h, lnmu, lnrs);
    {
        GArg g0 = {q1T, nullptr, nullptr, qb16, 4};
        GArg g1 = {nullptr, nullptr, nullptr, kb16, 0};
        GArg g2 = {nullptr, nullptr, nullptr, vt16, 0};
        gemm_t<1><<<dim3(15, 64, 1), 256, 0, stream>>>(h, 3, 320, lnmu, lnrs, ln1_w, ln1_b,
                                                       g0, g1, g2, nullptr, 4096, 320, 960, 4096);
    }
    attn_self5_k<<<dim3(64, 8, 2), 256, 0, stream>>>(qb16, kb16, vt16, Opart, lpart);
    // 3. o1 proj: A = combined 2-split partials, residual h
    {
        GArg g0 = {o1T, o1_b, h, nullptr, 0};
        gemm_t<2><<<dim3(5, 64, 1), 256, 0, stream>>>(Opart, 4, 0, lpart, nullptr, nullptr, nullptr,
                                                      g0, gz, gz, h, 4096, 320, 320, 0);
    }
    // 4. cross-attention block (LN2 in q2 staging)
    ln_stats_k<<<1024, 256, 0, stream>>>(h, lnmu, lnrs);
    {
        GArg g0 = {q2T, nullptr, nullptr, qb16, 1};
        gemm_t<3><<<dim3(5, 64, 1), 256, 0, stream>>>(h, 3, 320, lnmu, lnrs, ln2_w, ln2_b,
                                                      g0, gz, gz, nullptr, 4096, 320, 320, 0);
    }
    {
        GArg g0 = {k2T, nullptr, k2f, nullptr, 0};
        GArg g1 = {v2T, nullptr, v2f, nullptr, 0};
        gemm_t<4><<<dim3(5, 2, 2), 256, 0, stream>>>(ctx, 1, 768, nullptr, nullptr, nullptr, nullptr,
                                                     g0, g1, gz, nullptr, 77, 768, 320, 0);
    }
    attn_cross2_k<<<8192, 256, 0, stream>>>(qb16, k2f, v2f, ao16);
    {
        GArg g0 = {o2T, o2_b, h, nullptr, 0};
        gemm_t<5><<<dim3(5, 64, 1), 256, 0, stream>>>(ao16, 0, 320, nullptr, nullptr, nullptr, nullptr,
                                                      g0, gz, gz, h, 4096, 320, 320, 0);
    }
    // 5. GEGLU FF (LN3 in ff1 staging)
    ln_stats_k<<<1024, 256, 0, stream>>>(h, lnmu, lnrs);
    gemm_gg<<<dim3(20, 64, 1), 256, 0, stream>>>(h, 320, lnmu, lnrs, ln3_w, ln3_b,
                                                 ff1T, ff1_b, ffg16, 320, 1280, 1280);
    {
        GArg g0 = {ff2T, ff2_b, h, nullptr, 0};
        gemm_t<6><<<dim3(5, 64, 1), 256, 0, stream>>>(ffg16, 0, 1280, nullptr, nullptr, nullptr, nullptr,
                                                      g0, gz, gz, h, 4096, 1280, 320, 0);
    }
    // 6. proj_out + input residual
    {
        GArg g0 = {poutT, pout_b, out, nullptr, 3};
        gemm_t<7><<<dim3(5, 64, 1), 256, 0, stream>>>(h, 1, 320, nullptr, nullptr, nullptr, nullptr,
                                                      g0, gz, gz, x, 4096, 320, 320, 4096);
    }
}

// Round 12
// 505.460 us; speedup vs baseline: 1.2499x; 1.0151x over previous
//
#include <hip/hip_runtime.h>
#include <hip/hip_bf16.h>
#include <math.h>

#define N_SEQ  4096
#define DMODEL 320
#define NHEADS 8
#define DHEAD  40
#define CTXN   77
#define CTXD   768
#define FFI    1280

typedef short s8v __attribute__((ext_vector_type(8)));
typedef short s4v __attribute__((ext_vector_type(4)));
typedef float f4v __attribute__((ext_vector_type(4)));
typedef unsigned short u16;

static __device__ __forceinline__ u16 bf16u(float x) {           // RNE
    unsigned u = __float_as_uint(x);
    return (u16)((u + 0x7FFFu + ((u >> 16) & 1u)) >> 16);
}
static __device__ __forceinline__ float b2f(u16 v) { return __uint_as_float((unsigned)v << 16); }
static __device__ __forceinline__ unsigned pack2(float a, float b) {
    return (unsigned)bf16u(a) | ((unsigned)bf16u(b) << 16);
}

// ---------------- weight pre-convert v2: coalesced tiled transpose ----------------
struct WC { const float* s; u16* d; int K, O, trans; };
struct WCs { WC a[12]; };
__global__ __launch_bounds__(256) void wcast2_k(WCs P) {
    __shared__ float tile[32][33];
    WC w = P.a[blockIdx.y];
    if (w.trans) {
        int ntk = w.K >> 5, nto = w.O >> 5;
        int tid = blockIdx.x;
        if (tid >= ntk * nto) return;
        int tk = tid % ntk, to = tid / ntk;
        int lr = threadIdx.x >> 5, lc = threadIdx.x & 31;
#pragma unroll
        for (int p = 0; p < 4; ++p) {
            int k = tk * 32 + p * 8 + lr;
            tile[p * 8 + lr][lc] = w.s[(size_t)k * w.O + to * 32 + lc];
        }
        __syncthreads();
#pragma unroll
        for (int p = 0; p < 4; ++p) {
            int o = to * 32 + p * 8 + lr;
            w.d[(size_t)o * w.K + tk * 32 + lc] = bf16u(tile[lc][p * 8 + lr]);
        }
    } else {
        int nel = w.K * w.O;
        for (int e = blockIdx.x * 256 + threadIdx.x; e < nel; e += gridDim.x * 256)
            w.d[e] = bf16u(w.s[e]);
    }
}

// ---------------- GroupNorm stats -> per-channel scale/shift ----------------
__global__ __launch_bounds__(256) void gn_stats_k(const float* __restrict__ x,
                                                  const float* __restrict__ gw, const float* __restrict__ gb,
                                                  float* __restrict__ sc, float* __restrict__ sh) {
    __shared__ float red[512];
    __shared__ float ms[2];
    int g = blockIdx.x, t = threadIdx.x;
    const float* xp = x + (size_t)g * 40960;
    float s = 0.f, ss = 0.f;
    for (int i = t; i < 40960; i += 256) { float v = xp[i]; s += v; ss += v * v; }
    red[t] = s; red[256 + t] = ss;
    __syncthreads();
    for (int st = 128; st > 0; st >>= 1) {
        if (t < st) { red[t] += red[t + st]; red[256 + t] += red[256 + t + st]; }
        __syncthreads();
    }
    if (t == 0) {
        float mean = red[0] / 40960.f;
        float var  = red[256] / 40960.f - mean * mean;
        ms[0] = mean; ms[1] = rsqrtf(var + 1e-6f);
    }
    __syncthreads();
    if (t < 10) {
        int c = g * 10 + t;
        float scv = gw[c] * ms[1];
        sc[c] = scv;
        sh[c] = gb[c] - ms[0] * scv;
    }
}

// ---------------- LayerNorm stats ----------------
__global__ __launch_bounds__(256) void ln_stats_k(const float* __restrict__ in,
                                                  float* __restrict__ mu, float* __restrict__ rs) {
    int row = blockIdx.x * 4 + (threadIdx.x >> 6), l = threadIdx.x & 63;
    const float* p = in + (size_t)row * DMODEL;
    float s = 0.f, ss = 0.f;
#pragma unroll
    for (int j = 0; j < 5; ++j) { float v = p[l + 64 * j]; s += v; ss += v * v; }
    for (int o = 32; o > 0; o >>= 1) { s += __shfl_xor(s, o); ss += __shfl_xor(ss, o); }
    if (l == 0) {
        float mean = s * (1.f / 320.f);
        float var  = ss * (1.f / 320.f) - mean * mean;
        mu[row] = mean;
        rs[row] = rsqrtf(var + 1e-5f);
    }
}

struct GArg { const u16* Wt; const float* bias; float* outf; u16* outb; int ob_mode; };
#define GP 72

// ---------------- gemm_t<SITE>: 64x64 tile, K-chunk 64, reg-prefetch + LDS DOUBLE-BUFFER ----------------
// one barrier per K-chunk.
template<int SITE>
__global__ __launch_bounds__(256) void gemm_t(const void* __restrict__ Av, int a_mode, int lda,
                                              const float* __restrict__ mu, const float* __restrict__ rs,
                                              const float* __restrict__ cw, const float* __restrict__ cb,
                                              GArg g0, GArg g1, GArg g2,
                                              const float* __restrict__ res,
                                              int Mrows, int K, int Oout, int obT_stride) {
    __shared__ __align__(16) u16 As[2][64 * GP];
    __shared__ __align__(16) u16 Wsm[2][64 * GP];
    const int t = threadIdx.x;
    const int w = t >> 6, lane = t & 63, c = lane & 15, quad = lane >> 4;
    const int o0 = blockIdx.x * 64, n0 = blockIdx.y * 64;
    GArg g = (blockIdx.z == 0) ? g0 : ((blockIdx.z == 1) ? g1 : g2);
    const f4v zero = {0.f, 0.f, 0.f, 0.f};
    f4v acc[4] = {zero, zero, zero, zero};
    const s8v z8 = {0, 0, 0, 0, 0, 0, 0, 0};
    const int nk = K >> 6;

    float fA[16];
    s8v bA0 = z8, bA1 = z8;
    s8v wv0, wv1;

    auto loadW = [&](int k0) {
        int i0 = t, i1 = t + 256;
        wv0 = *(const s8v*)(g.Wt + (size_t)(o0 + (i0 >> 3)) * K + k0 + (i0 & 7) * 8);
        wv1 = *(const s8v*)(g.Wt + (size_t)(o0 + (i1 >> 3)) * K + k0 + (i1 & 7) * 8);
    };
    auto storeW = [&](int b) {
        int i0 = t, i1 = t + 256;
        *(s8v*)&Wsm[b][(i0 >> 3) * GP + (i0 & 7) * 8] = wv0;
        *(s8v*)&Wsm[b][(i1 >> 3) * GP + (i1 & 7) * 8] = wv1;
    };
    auto loadA = [&](int k0) {
        if (a_mode == 0) {
            const u16* A = (const u16*)Av;
            int i0 = t, i1 = t + 256;
            int nA = n0 + (i0 >> 3), nB = n0 + (i1 >> 3);
            bA0 = (nA < Mrows) ? *(const s8v*)(A + (size_t)nA * lda + k0 + (i0 & 7) * 8) : z8;
            bA1 = (nB < Mrows) ? *(const s8v*)(A + (size_t)nB * lda + k0 + (i1 & 7) * 8) : z8;
        } else if (a_mode == 1) {
            const float* A = (const float*)Av;
            int r = t >> 2, s16 = (t & 3) * 16;
            int n = n0 + r;
            if (n < Mrows) {
                const float* src = A + (size_t)n * lda + k0 + s16;
#pragma unroll
                for (int i = 0; i < 16; ++i) fA[i] = src[i];
            } else {
#pragma unroll
                for (int i = 0; i < 16; ++i) fA[i] = 0.f;
            }
        } else if (a_mode == 2) {
            const float* A = (const float*)Av;
#pragma unroll
            for (int j = 0; j < 16; ++j) {
                int e = t + 256 * j; int nn = e & 63, kk = e >> 6;
                int n = n0 + nn, kgl = k0 + kk;
                fA[j] = (n < Mrows) ? A[(size_t)kgl * lda + n] * cw[kgl] + cb[kgl] : 0.f;
            }
        } else if (a_mode == 3) {
            const float* A = (const float*)Av;
            int r = t >> 2, s16 = (t & 3) * 16;
            int n = n0 + r;
            if (n < Mrows) {
                const float* src = A + (size_t)n * lda + k0 + s16;
                const float* cwp = cw + k0 + s16;
                const float* cbp = cb + k0 + s16;
                float m_ = mu[n], rr = rs[n];
#pragma unroll
                for (int i = 0; i < 16; ++i) fA[i] = (src[i] - m_) * rr * cwp[i] + cbp[i];
            } else {
#pragma unroll
                for (int i = 0; i < 16; ++i) fA[i] = 0.f;
            }
        } else {   // 4: 2-split attention combine
            const u16* Op = (const u16*)Av;
            const float* lp = mu;
            int r = t >> 2, s16 = (t & 3) * 16;
            int n = n0 + r;
            int ch0 = k0 + s16;
            int hdA = ch0 / 40;
            int hdB = (ch0 + 15) / 40;
            float invA = 1.f / (lp[(size_t)hdA * N_SEQ + n] + lp[(size_t)(8 + hdA) * N_SEQ + n]);
            float invB = (hdB == hdA) ? invA
                       : 1.f / (lp[(size_t)hdB * N_SEQ + n] + lp[(size_t)(8 + hdB) * N_SEQ + n]);
#pragma unroll
            for (int i = 0; i < 16; ++i) {
                int ch = ch0 + i;
                int hd = ch / 40;
                int d  = ch - hd * 40;
                float num = b2f(Op[((size_t)hd * N_SEQ + n) * DHEAD + d])
                          + b2f(Op[((size_t)(8 + hd) * N_SEQ + n) * DHEAD + d]);
                fA[i] = num * ((hd == hdA) ? invA : invB);
            }
        }
    };
    auto storeA = [&](int b) {
        if (a_mode == 0) {
            int i0 = t, i1 = t + 256;
            *(s8v*)&As[b][(i0 >> 3) * GP + (i0 & 7) * 8] = bA0;
            *(s8v*)&As[b][(i1 >> 3) * GP + (i1 & 7) * 8] = bA1;
        } else if (a_mode == 2) {
#pragma unroll
            for (int j = 0; j < 16; ++j) {
                int e = t + 256 * j; int nn = e & 63, kk = e >> 6;
                As[b][nn * GP + kk] = bf16u(fA[j]);
            }
        } else {
            int r = t >> 2, s16 = (t & 3) * 16;
            unsigned* dst = (unsigned*)&As[b][r * GP + s16];
#pragma unroll
            for (int i = 0; i < 8; ++i) dst[i] = pack2(fA[2 * i], fA[2 * i + 1]);
        }
    };

    // pipeline with double buffer: one barrier per chunk
    loadA(0); loadW(0);
    storeA(0); storeW(0);
    __syncthreads();
    for (int k = 0; k < nk; ++k) {
        const int cur = k & 1;
        if (k + 1 < nk) { loadA((k + 1) << 6); loadW((k + 1) << 6); }
        s8v a0 = *(const s8v*)&As[cur][(w * 16 + c) * GP + quad * 8];
        s8v a1 = *(const s8v*)&As[cur][(w * 16 + c) * GP + 32 + quad * 8];
#pragma unroll
        for (int nt = 0; nt < 4; ++nt) {
            s8v b0 = *(const s8v*)&Wsm[cur][(nt * 16 + c) * GP + quad * 8];
            s8v b1 = *(const s8v*)&Wsm[cur][(nt * 16 + c) * GP + 32 + quad * 8];
            acc[nt] = __builtin_amdgcn_mfma_f32_16x16x32_bf16(a0, b0, acc[nt], 0, 0, 0);
            acc[nt] = __builtin_amdgcn_mfma_f32_16x16x32_bf16(a1, b1, acc[nt], 0, 0, 0);
        }
        if (k + 1 < nk) { storeA(1 - cur); storeW(1 - cur); }
        __syncthreads();
    }
    // ---------- epilogue ----------
#pragma unroll
    for (int nt = 0; nt < 4; ++nt) {
        int o = o0 + nt * 16 + c;
        float vv[4];
#pragma unroll
        for (int r = 0; r < 4; ++r) vv[r] = acc[nt][r] + (g.bias ? g.bias[o] : 0.f);
        if (g.ob_mode == 3) {
            int nb = n0 + w * 16 + quad * 4;
            const float4 x4 = *(const float4*)(res + (size_t)o * obT_stride + nb);
            float4 o4 = make_float4(vv[0] + x4.x, vv[1] + x4.y, vv[2] + x4.z, vv[3] + x4.w);
            *(float4*)(g.outf + (size_t)o * obT_stride + nb) = o4;
        } else if (g.ob_mode == 4) {
#pragma unroll
            for (int r = 0; r < 4; ++r) {
                int n = n0 + w * 16 + quad * 4 + r;
                u16 bv = bf16u(vv[r]);
                if (o < 320)      g0.outb[(size_t)n * 320 + o] = bv;
                else if (o < 640) g1.outb[(size_t)n * 320 + (o - 320)] = bv;
                else              g2.outb[(size_t)(o - 640) * obT_stride + n] = bv;
            }
        } else {
#pragma unroll
            for (int r = 0; r < 4; ++r) {
                int n = n0 + w * 16 + quad * 4 + r;
                if (n >= Mrows) continue;
                float v = vv[r];
                if (res) v += res[(size_t)n * Oout + o];
                if (g.outf) g.outf[(size_t)n * Oout + o] = v;
                if (g.ob_mode == 1) g.outb[(size_t)n * Oout + o] = bf16u(v);
                else if (g.ob_mode == 2) g.outb[(size_t)o * obT_stride + n] = bf16u(v);
            }
        }
    }
}

// ---------------- gemm_gg: ff1 GEGLU (LN staging), register-prefetch pipeline (single buffer) ---------
__global__ __launch_bounds__(256) void gemm_gg(const float* __restrict__ A, int lda,
                                               const float* __restrict__ mu, const float* __restrict__ rs,
                                               const float* __restrict__ cw, const float* __restrict__ cb,
                                               const u16* __restrict__ Wt, const float* __restrict__ bias,
                                               u16* __restrict__ outb,
                                               int K, int Oout, int geglu_off) {
    __shared__ __align__(16) u16 As[64 * GP];
    __shared__ __align__(16) u16 Wsm[64 * GP];
    __shared__ __align__(16) u16 Wgm[64 * GP];
    const int t = threadIdx.x;
    const int w = t >> 6, lane = t & 63, c = lane & 15, quad = lane >> 4;
    const int o0 = blockIdx.x * 64, n0 = blockIdx.y * 64;
    const f4v zero = {0.f, 0.f, 0.f, 0.f};
    f4v acc[4]  = {zero, zero, zero, zero};
    f4v accg[4] = {zero, zero, zero, zero};
    const int nk = K >> 6;

    float fA[16];
    s8v wv0, wv1, gv0, gv1;

    auto loadWG = [&](int k0) {
        int i0 = t, i1 = t + 256;
        wv0 = *(const s8v*)(Wt + (size_t)(o0 + (i0 >> 3)) * K + k0 + (i0 & 7) * 8);
        wv1 = *(const s8v*)(Wt + (size_t)(o0 + (i1 >> 3)) * K + k0 + (i1 & 7) * 8);
        gv0 = *(const s8v*)(Wt + (size_t)(o0 + (i0 >> 3) + geglu_off) * K + k0 + (i0 & 7) * 8);
        gv1 = *(const s8v*)(Wt + (size_t)(o0 + (i1 >> 3) + geglu_off) * K + k0 + (i1 & 7) * 8);
    };
    auto storeWG = [&]() {
        int i0 = t, i1 = t + 256;
        *(s8v*)&Wsm[(i0 >> 3) * GP + (i0 & 7) * 8] = wv0;
        *(s8v*)&Wsm[(i1 >> 3) * GP + (i1 & 7) * 8] = wv1;
        *(s8v*)&Wgm[(i0 >> 3) * GP + (i0 & 7) * 8] = gv0;
        *(s8v*)&Wgm[(i1 >> 3) * GP + (i1 & 7) * 8] = gv1;
    };
    auto loadA = [&](int k0) {
        int r = t >> 2, s16 = (t & 3) * 16;
        int n = n0 + r;
        const float* src = A + (size_t)n * lda + k0 + s16;
        const float* cwp = cw + k0 + s16;
        const float* cbp = cb + k0 + s16;
        float m_ = mu[n], rr = rs[n];
#pragma unroll
        for (int i = 0; i < 16; ++i) fA[i] = (src[i] - m_) * rr * cwp[i] + cbp[i];
    };
    auto storeA = [&]() {
        int r = t >> 2, s16 = (t & 3) * 16;
        unsigned* dst = (unsigned*)&As[r * GP + s16];
#pragma unroll
        for (int i = 0; i < 8; ++i) dst[i] = pack2(fA[2 * i], fA[2 * i + 1]);
    };

    loadA(0); loadWG(0);
    storeA(); storeWG();
    __syncthreads();
    for (int k = 0; k < nk; ++k) {
        if (k + 1 < nk) { loadA((k + 1) << 6); loadWG((k + 1) << 6); }
        s8v a0 = *(const s8v*)&As[(w * 16 + c) * GP + quad * 8];
        s8v a1 = *(const s8v*)&As[(w * 16 + c) * GP + 32 + quad * 8];
#pragma unroll
        for (int nt = 0; nt < 4; ++nt) {
            s8v b0 = *(const s8v*)&Wsm[(nt * 16 + c) * GP + quad * 8];
            s8v b1 = *(const s8v*)&Wsm[(nt * 16 + c) * GP + 32 + quad * 8];
            acc[nt] = __builtin_amdgcn_mfma_f32_16x16x32_bf16(a0, b0, acc[nt], 0, 0, 0);
            acc[nt] = __builtin_amdgcn_mfma_f32_16x16x32_bf16(a1, b1, acc[nt], 0, 0, 0);
            s8v q0 = *(const s8v*)&Wgm[(nt * 16 + c) * GP + quad * 8];
            s8v q1 = *(const s8v*)&Wgm[(nt * 16 + c) * GP + 32 + quad * 8];
            accg[nt] = __builtin_amdgcn_mfma_f32_16x16x32_bf16(a0, q0, accg[nt], 0, 0, 0);
            accg[nt] = __builtin_amdgcn_mfma_f32_16x16x32_bf16(a1, q1, accg[nt], 0, 0, 0);
        }
        __syncthreads();
        if (k + 1 < nk) {
            storeA(); storeWG();
            __syncthreads();
        }
    }
#pragma unroll
    for (int nt = 0; nt < 4; ++nt) {
        int o = o0 + nt * 16 + c;
#pragma unroll
        for (int r = 0; r < 4; ++r) {
            int n = n0 + w * 16 + quad * 4 + r;
            float v = acc[nt][r] + bias[o];
            float gg = accg[nt][r] + bias[o + geglu_off];
            v = v * 0.5f * gg * (1.f + erff(gg * 0.70710678118654752f));
            outb[(size_t)n * Oout + o] = bf16u(v);
        }
    }
}

// ---------------- Self-attention v7: 2-split, 31KB LDS, l via PV-ones MFMA, truncated P ----------------
#define KSP 40
#define PSP 140
#define VP  136
__global__ __launch_bounds__(256) void attn_self7_k(const u16* __restrict__ qb, const u16* __restrict__ kb,
                                                    const u16* __restrict__ vt,
                                                    u16* __restrict__ Opart, float* __restrict__ lpart) {
    __shared__ __align__(16) u16 KsPs[64 * PSP];
    __shared__ __align__(16) u16 Vs[48 * VP];
    const int t = threadIdx.x;
    const int w = t >> 6, lane = t & 63, c = lane & 15, quad = lane >> 4;
    const int hd = blockIdx.y, ks = blockIdx.z;
    const int q0 = blockIdx.x * 64;
    const float SC2 = 0.15811388300841897f * 1.4426950408889634f;
    const f4v zero = {0.f, 0.f, 0.f, 0.f};
    const s8v z8 = {0, 0, 0, 0, 0, 0, 0, 0};

    // zero pad rows 41..47; row 40 = 1.0 (PV-ones: col 40 of O accumulates sum(P) = l)
    for (int i = t; i < 8 * VP / 2; i += 256) ((unsigned*)&Vs[40 * VP])[i] = 0u;
    __syncthreads();
    if (t < VP) Vs[40 * VP + t] = (u16)0x3F80;

    const u16* qrow = qb + (size_t)(q0 + w * 16 + c) * DMODEL + hd * DHEAD;
    s8v qa0 = *(const s8v*)(qrow + quad * 8);
    s8v qa1 = z8;
    if (quad == 0) qa1 = *(const s8v*)(qrow + 32);

    f4v o0 = zero, o1 = zero, o2 = zero;

    for (int kt = 0; kt < 16; ++kt) {
        const int k0 = ks * 2048 + kt * 128;
        __syncthreads();
        for (int i = t; i < 640; i += 256) {
            int r = i / 5, sg = i - r * 5;
            *(s8v*)&KsPs[r * KSP + sg * 8] = *(const s8v*)(kb + (size_t)(k0 + r) * DMODEL + hd * DHEAD + sg * 8);
        }
        for (int i = t; i < 640; i += 256) {
            int d = i >> 4, sg = i & 15;
            *(s8v*)&Vs[d * VP + sg * 8] = *(const s8v*)(vt + (size_t)(hd * DHEAD + d) * N_SEQ + k0 + sg * 8);
        }
        __syncthreads();

        f4v sarr[8];
#pragma unroll
        for (int nt = 0; nt < 8; ++nt) {
            const int kr = nt * 16 + c;
            s8v b0 = *(const s8v*)&KsPs[kr * KSP + quad * 8];
            s8v b1 = z8;
            if (quad == 0) b1 = *(const s8v*)&KsPs[kr * KSP + 32];
            f4v s = __builtin_amdgcn_mfma_f32_16x16x32_bf16(qa0, b0, zero, 0, 0, 0);
            s = __builtin_amdgcn_mfma_f32_16x16x32_bf16(qa1, b1, s, 0, 0, 0);
            sarr[nt] = s;
        }
        __syncthreads();

        u16* psw = &KsPs[(size_t)(w * 16 + quad * 4) * PSP + c];
#pragma unroll
        for (int reg = 0; reg < 8; ++reg) {
            const int colb = (reg >> 2) * 64 + (reg & 3) * 16;
#pragma unroll
            for (int r = 0; r < 4; ++r) {
                float pv = exp2f(sarr[reg][r] * SC2);
                psw[r * PSP + colb] = (u16)(__float_as_uint(pv) >> 16);   // truncate
            }
        }

        const u16* prow = &KsPs[(size_t)(w * 16 + c) * PSP];
#pragma unroll
        for (int h2 = 0; h2 < 2; ++h2) {
            s8v pa0, pa1;
            {
                s4v lo = *(const s4v*)(prow + h2 * 64 + quad * 8);
                s4v hi = *(const s4v*)(prow + h2 * 64 + quad * 8 + 4);
                pa0 = (s8v){lo[0], lo[1], lo[2], lo[3], hi[0], hi[1], hi[2], hi[3]};
                s4v lo2 = *(const s4v*)(prow + h2 * 64 + 32 + quad * 8);
                s4v hi2 = *(const s4v*)(prow + h2 * 64 + 32 + quad * 8 + 4);
                pa1 = (s8v){lo2[0], lo2[1], lo2[2], lo2[3], hi2[0], hi2[1], hi2[2], hi2[3]};
            }
            {
                s8v v0 = *(const s8v*)&Vs[(0 * 16 + c) * VP + h2 * 64 + quad * 8];
                s8v v1 = *(const s8v*)&Vs[(0 * 16 + c) * VP + h2 * 64 + 32 + quad * 8];
                o0 = __builtin_amdgcn_mfma_f32_16x16x32_bf16(pa0, v0, o0, 0, 0, 0);
                o0 = __builtin_amdgcn_mfma_f32_16x16x32_bf16(pa1, v1, o0, 0, 0, 0);
            }
            {
                s8v v0 = *(const s8v*)&Vs[(1 * 16 + c) * VP + h2 * 64 + quad * 8];
                s8v v1 = *(const s8v*)&Vs[(1 * 16 + c) * VP + h2 * 64 + 32 + quad * 8];
                o1 = __builtin_amdgcn_mfma_f32_16x16x32_bf16(pa0, v0, o1, 0, 0, 0);
                o1 = __builtin_amdgcn_mfma_f32_16x16x32_bf16(pa1, v1, o1, 0, 0, 0);
            }
            {
                s8v v0 = *(const s8v*)&Vs[(2 * 16 + c) * VP + h2 * 64 + quad * 8];
                s8v v1 = *(const s8v*)&Vs[(2 * 16 + c) * VP + h2 * 64 + 32 + quad * 8];
                o2 = __builtin_amdgcn_mfma_f32_16x16x32_bf16(pa0, v0, o2, 0, 0, 0);
                o2 = __builtin_amdgcn_mfma_f32_16x16x32_bf16(pa1, v1, o2, 0, 0, 0);
            }
        }
    }

    const size_t pb = (size_t)(ks * 8 + hd) * N_SEQ;
#pragma unroll
    for (int r = 0; r < 4; ++r) {
        int q = q0 + w * 16 + quad * 4 + r;
        u16* op = Opart + (pb + q) * DHEAD;
        op[c]      = bf16u(o0[r]);
        op[16 + c] = bf16u(o1[r]);
        if (c < 8) op[32 + c] = bf16u(o2[r]);
        if (c == 8) lpart[pb + q] = o2[r];   // col 40 = sum(P) via ones-row
    }
}

// ---------------- Cross-attention (M=77) ----------------
__global__ __launch_bounds__(256) void attn_cross2_k(const u16* __restrict__ q, const float* __restrict__ kc,
                                                     const float* __restrict__ vc, u16* __restrict__ out) {
    __shared__ float Pl[4][128];
    const int t = threadIdx.x, w = t >> 6, l = t & 63;
    const int gw = blockIdx.x * 4 + w;
    const int row = gw >> 3, hd = gw & 7;
    const float scale = 0.15811388300841897f;
    float qv[40];
    {
        const u16* qp = q + (size_t)row * DMODEL + hd * DHEAD;
#pragma unroll
        for (int i = 0; i < 5; ++i) {
            s8v v8 = *(const s8v*)(qp + i * 8);
#pragma unroll
            for (int j = 0; j < 8; ++j) qv[i * 8 + j] = b2f((u16)v8[j]) * scale;
        }
    }
    float s1 = -1e30f, s2 = -1e30f;
    if (l < CTXN) {
        const float* kp = kc + (size_t)l * DMODEL + hd * DHEAD;
        float s = 0.f;
#pragma unroll
        for (int i = 0; i < 40; ++i) s += qv[i] * kp[i];
        s1 = s;
    }
    if (l + 64 < CTXN) {
        const float* kp = kc + (size_t)(l + 64) * DMODEL + hd * DHEAD;
        float s = 0.f;
#pragma unroll
        for (int i = 0; i < 40; ++i) s += qv[i] * kp[i];
        s2 = s;
    }
    float mx = fmaxf(s1, s2);
    for (int o = 32; o > 0; o >>= 1) mx = fmaxf(mx, __shfl_xor(mx, o));
    float p1 = (l < CTXN) ? __expf(s1 - mx) : 0.f;
    float p2 = (l + 64 < CTXN) ? __expf(s2 - mx) : 0.f;
    float ps = p1 + p2;
    for (int o = 32; o > 0; o >>= 1) ps += __shfl_xor(ps, o);
    Pl[w][l] = p1;
    Pl[w][l + 64] = p2;
    if (l < DHEAD) {
        float acc = 0.f;
        for (int j = 0; j < CTXN; ++j) acc += Pl[w][j] * vc[(size_t)j * DMODEL + hd * DHEAD + l];
        out[(size_t)row * DMODEL + hd * DHEAD + l] = bf16u(acc / ps);
    }
}

extern "C" void kernel_launch(void* const* d_in, const int* in_sizes, int n_in,
                              void* d_out, int out_size, void* d_ws, size_t ws_size,
                              hipStream_t stream) {
    const float* x      = (const float*)d_in[0];
    const float* ctx    = (const float*)d_in[1];
    const float* gn_w   = (const float*)d_in[2];
    const float* gn_b   = (const float*)d_in[3];
    const float* pin_w  = (const float*)d_in[4];
    const float* pin_b  = (const float*)d_in[5];
    const float* ln1_w  = (const float*)d_in[6];
    const float* ln1_b  = (const float*)d_in[7];
    const float* q1     = (const float*)d_in[8];
    const float* k1     = (const float*)d_in[9];
    const float* v1     = (const float*)d_in[10];
    const float* o1_w   = (const float*)d_in[11];
    const float* o1_b   = (const float*)d_in[12];
    const float* ln2_w  = (const float*)d_in[13];
    const float* ln2_b  = (const float*)d_in[14];
    const float* q2     = (const float*)d_in[15];
    const float* k2     = (const float*)d_in[16];
    const float* v2     = (const float*)d_in[17];
    const float* o2_w   = (const float*)d_in[18];
    const float* o2_b   = (const float*)d_in[19];
    const float* ln3_w  = (const float*)d_in[20];
    const float* ln3_b  = (const float*)d_in[21];
    const float* ff1_w  = (const float*)d_in[22];
    const float* ff1_b  = (const float*)d_in[23];
    const float* ff2_w  = (const float*)d_in[24];
    const float* ff2_b  = (const float*)d_in[25];
    const float* pout_w = (const float*)d_in[26];
    const float* pout_b = (const float*)d_in[27];
    float* out = (float*)d_out;

    char* base = (char*)d_ws;
    float* h     = (float*)(base);
    u16*   qb16  = (u16*)(base + 5242880);
    u16*   kb16  = (u16*)(base + 7864320);
    u16*   vt16  = (u16*)(base + 10485760);
    u16*   ao16  = (u16*)(base + 13107200);
    u16*   ffg16 = (u16*)(base + 5242880);
    u16*   wbase = (u16*)(base + 15728640);
    u16* pinT  = wbase;
    u16* q1T   = pinT  + 102400;
    u16* k1T   = q1T   + 102400;
    u16* v1T   = k1T   + 102400;
    u16* o1T   = v1T   + 102400;
    u16* q2T   = o1T   + 102400;
    u16* o2T   = q2T   + 102400;
    u16* k2T   = o2T   + 102400;
    u16* v2T   = k2T   + 245760;
    u16* ff1T  = v2T   + 245760;
    u16* ff2T  = ff1T  + 819200;
    u16* poutT = ff2T  + 409600;
    float* lnmu = (float*)(base + 20807680);
    float* lnrs = lnmu + 4096;
    float* k2f  = lnrs + 4096;
    float* v2f  = k2f + 25600;
    u16*   Opart = (u16*)(v2f + 25600);
    float* lpart = (float*)(Opart + (size_t)2 * 8 * 4096 * 40);
    float* gnsc  = lpart + 2 * 8 * 4096;
    float* gnsh  = gnsc + 320;

    WCs wd;
    wd.a[0]  = {pin_w,  pinT,  320,  320,  0};
    wd.a[1]  = {q1,     q1T,   320,  320,  1};
    wd.a[2]  = {k1,     k1T,   320,  320,  1};
    wd.a[3]  = {v1,     v1T,   320,  320,  1};
    wd.a[4]  = {o1_w,   o1T,   320,  320,  1};
    wd.a[5]  = {q2,     q2T,   320,  320,  1};
    wd.a[6]  = {o2_w,   o2T,   320,  320,  1};
    wd.a[7]  = {k2,     k2T,   768,  320,  1};
    wd.a[8]  = {v2,     v2T,   768,  320,  1};
    wd.a[9]  = {ff1_w,  ff1T,  320,  2560, 1};
    wd.a[10] = {ff2_w,  ff2T,  1280, 320,  1};
    wd.a[11] = {pout_w, poutT, 320,  320,  0};
    wcast2_k<<<dim3(800, 12), 256, 0, stream>>>(wd);

    GArg gz = {nullptr, nullptr, nullptr, nullptr, 0};

    // 1. GN stats; proj_in (GN fused in staging)
    gn_stats_k<<<32, 256, 0, stream>>>(x, gn_w, gn_b, gnsc, gnsh);
    {
        GArg g0 = {pinT, pin_b, h, nullptr, 0};
        gemm_t<0><<<dim3(5, 64, 1), 256, 0, stream>>>(x, 2, 4096, nullptr, nullptr, gnsc, gnsh,
                                                      g0, gz, gz, nullptr, 4096, 320, 320, 0);
    }
    // 2. qkv fused (LN1 in staging)
    ln_stats_k<<<1024, 256, 0, stream>>>(h, lnmu, lnrs);
    {
        GArg g0 = {q1T, nullptr, nullptr, qb16, 4};
        GArg g1 = {nullptr, nullptr, nullptr, kb16, 0};
        GArg g2 = {nullptr, nullptr, nullptr, vt16, 0};
        gemm_t<1><<<dim3(15, 64, 1), 256, 0, stream>>>(h, 3, 320, lnmu, lnrs, ln1_w, ln1_b,
                                                       g0, g1, g2, nullptr, 4096, 320, 960, 4096);
    }
    attn_self7_k<<<dim3(64, 8, 2), 256, 0, stream>>>(qb16, kb16, vt16, Opart, lpart);
    // 3. o1 proj: A = combined 2-split partials, residual h
    {
        GArg g0 = {o1T, o1_b, h, nullptr, 0};
        gemm_t<2><<<dim3(5, 64, 1), 256, 0, stream>>>(Opart, 4, 0, lpart, nullptr, nullptr, nullptr,
                                                      g0, gz, gz, h, 4096, 320, 320, 0);
    }
    // 4. cross-attention block (LN2 in q2 staging)
    ln_stats_k<<<1024, 256, 0, stream>>>(h, lnmu, lnrs);
    {
        GArg g0 = {q2T, nullptr, nullptr, qb16, 1};
        gemm_t<3><<<dim3(5, 64, 1), 256, 0, stream>>>(h, 3, 320, lnmu, lnrs, ln2_w, ln2_b,
                                                      g0, gz, gz, nullptr, 4096, 320, 320, 0);
    }
    {
        GArg g0 = {k2T, nullptr, k2f, nullptr, 0};
        GArg g1 = {v2T, nullptr, v2f, nullptr, 0};
        gemm_t<4><<<dim3(5, 2, 2), 256, 0, stream>>>(ctx, 1, 768, nullptr, nullptr, nullptr, nullptr,
                                                     g0, g1, gz, nullptr, 77, 768, 320, 0);
    }
    attn_cross2_k<<<8192, 256, 0, stream>>>(qb16, k2f, v2f, ao16);
    {
        GArg g0 = {o2T, o2_b, h, nullptr, 0};
        gemm_t<5><<<dim3(5, 64, 1), 256, 0, stream>>>(ao16, 0, 320, nullptr, nullptr, nullptr, nullptr,
                                                      g0, gz, gz, h, 4096, 320, 320, 0);
    }
    // 5. GEGLU FF (LN3 in ff1 staging)
    ln_stats_k<<<1024, 256, 0, stream>>>(h, lnmu, lnrs);
    gemm_gg<<<dim3(20, 64, 1), 256, 0, stream>>>(h, 320, lnmu, lnrs, ln3_w, ln3_b,
                                                 ff1T, ff1_b, ffg16, 320, 1280, 1280);
    {
        GArg g0 = {ff2T, ff2_b, h, nullptr, 0};
        gemm_t<6><<<dim3(5, 64, 1), 256, 0, stream>>>(ffg16, 0, 1280, nullptr, nullptr, nullptr, nullptr,
                                                      g0, gz, gz, h, 4096, 1280, 320, 0);
    }
    // 6. proj_out + input residual
    {
        GArg g0 = {poutT, pout_b, out, nullptr, 3};
        gemm_t<7><<<dim3(5, 64, 1), 256, 0, stream>>>(h, 1, 320, nullptr, nullptr, nullptr, nullptr,
                                                      g0, gz, gz, x, 4096, 320, 320, 4096);
    }
}